// Round 2
// baseline (1151.985 us; speedup 1.0000x reference)
//
#include <hip/hip_runtime.h>
#include <cstdint>

using u16 = unsigned short;
using u32 = unsigned int;
typedef __attribute__((ext_vector_type(8))) short short8;
typedef __attribute__((ext_vector_type(4))) float f32x4;

__device__ __forceinline__ float bf2f(u16 u) { return __uint_as_float(((u32)u) << 16); }
__device__ __forceinline__ u16 f2bf(float f) {
    u32 u = __float_as_uint(f);
    u32 r = u + 0x7fffu + ((u >> 16) & 1u);   // round-to-nearest-even
    return (u16)(r >> 16);
}

__device__ __forceinline__ void load_lds16(const void* g, void* l) {
    __builtin_amdgcn_global_load_lds((const __attribute__((address_space(1))) void*)g,
                                     (__attribute__((address_space(3))) void*)l, 16, 0, 0);
}

// ---------------- LayerNorm row body (1024 fp32 -> bf16) ----------------
__device__ __forceinline__ void ln_row(const float* __restrict__ x,
                                       const float* __restrict__ gw,
                                       const float* __restrict__ bw,
                                       u16* __restrict__ y, int row) {
    const int tid = threadIdx.x;
    const float4 v = ((const float4*)(x + (size_t)row * 1024))[tid];
    float s  = v.x + v.y + v.z + v.w;
    float ss = v.x * v.x + v.y * v.y + v.z * v.z + v.w * v.w;
#pragma unroll
    for (int off = 32; off; off >>= 1) {
        s  += __shfl_xor(s, off);
        ss += __shfl_xor(ss, off);
    }
    __shared__ float sm[8];
    const int lane = tid & 63, wid = tid >> 6;
    if (lane == 0) { sm[wid] = s; sm[wid + 4] = ss; }
    __syncthreads();
    s  = sm[0] + sm[1] + sm[2] + sm[3];
    ss = sm[4] + sm[5] + sm[6] + sm[7];
    const float mu   = s * (1.0f / 1024.0f);
    const float var  = ss * (1.0f / 1024.0f) - mu * mu;
    const float rstd = rsqrtf(var + 1e-5f);
    const float4 g4 = ((const float4*)gw)[tid];
    const float4 b4 = ((const float4*)bw)[tid];
    u16 o[4];
    o[0] = f2bf((v.x - mu) * rstd * g4.x + b4.x);
    o[1] = f2bf((v.y - mu) * rstd * g4.y + b4.y);
    o[2] = f2bf((v.z - mu) * rstd * g4.z + b4.z);
    o[3] = f2bf((v.w - mu) * rstd * g4.w + b4.w);
    *(uint2*)(y + (size_t)row * 1024 + tid * 4) = *(uint2*)o;
}

__global__ __launch_bounds__(256)
void ln_cast_kernel(const float* __restrict__ x, const float* __restrict__ gw,
                    const float* __restrict__ bw, u16* __restrict__ y) {
    ln_row(x, gw, bw, y, blockIdx.x);
}

// merged: all 3 layernorms in one dispatch (sel = bid>>14)
__global__ __launch_bounds__(256)
void ln3_kernel(const float* __restrict__ x0, const float* __restrict__ x1,
                const float* __restrict__ x2,
                const float* __restrict__ g0, const float* __restrict__ g1,
                const float* __restrict__ g2,
                const float* __restrict__ b0, const float* __restrict__ b1,
                const float* __restrict__ b2, u16* __restrict__ y) {
    const int bid = blockIdx.x;
    const int sel = bid >> 14;
    const int row = bid & 16383;
    const float* x  = (sel == 0) ? x0 : (sel == 1) ? x1 : x2;
    const float* gw = (sel == 0) ? g0 : (sel == 1) ? g1 : g2;
    const float* bw = (sel == 0) ? b0 : (sel == 1) ? b1 : b2;
    ln_row(x, gw, bw, y + ((size_t)sel << 24), row);
}

// ---------------- fp32 -> bf16 cast of the 3 weight matrices ----------------
__global__ __launch_bounds__(256)
void cast3_kernel(const float* __restrict__ wa, const float* __restrict__ wb,
                  const float* __restrict__ wc, u16* __restrict__ oa) {
    const int bid = blockIdx.x;
    const int sel = bid >> 10;
    const float* s = (sel == 0) ? wa : (sel == 1) ? wb : wc;
    u16* d = oa + (size_t)sel * 1048576;
    const int i = (bid & 1023) * 256 + threadIdx.x;
    const float4 v = ((const float4*)s)[i];
    u16 o[4] = { f2bf(v.x), f2bf(v.y), f2bf(v.z), f2bf(v.w) };
    *(uint2*)(d + (size_t)i * 4) = *(uint2*)o;
}

// ---------------- old 128x128 GEMM (kept for MODE 3 / fallback) -----------
template<int MODE>
__global__ __launch_bounds__(256, (MODE == 3 ? 3 : 4))
void gemm_bt(const u16* __restrict__ A, const u16* __restrict__ B,
             const float* __restrict__ bias0, const float* __restrict__ bias1,
             const float* __restrict__ bias2,
             void* __restrict__ Cout, void* __restrict__ Cout2,
             const int M, const int N, const int K, const float scale,
             const long sA, const long sB, const long sC)
{
    int bz, m0, n0;
    if (MODE == 2 || MODE == 3) {
        const int id = blockIdx.x;
        bz = id & 7;                      // one batch per XCD
        m0 = ((id >> 3) & 15) * 128;
        n0 = (id >> 7) * 128;
    } else {
        bz = (MODE == 4) ? blockIdx.z : 0;
        m0 = blockIdx.x * 128;
        n0 = blockIdx.y * 128;
    }
    A += (long)bz * sA;
    B += (long)bz * sB;
    const float* bias = (MODE == 4) ? (bz == 0 ? bias0 : bz == 1 ? bias1 : bias2)
                                    : bias0;
    __shared__ __align__(16) u16 As[128 * 64];
    __shared__ __align__(16) u16 Bs[128 * 64];
    const int tid  = threadIdx.x;
    const int lane = tid & 63, wid = tid >> 6;
    const int wm = (wid & 1) * 64, wn = (wid >> 1) * 64;

    const int scol = (tid & 7) ^ ((tid >> 3) & 7);
    const u16* ap = A + (long)(m0 + (tid >> 3)) * K + scol * 8;
    const u16* bp = B + (long)(n0 + (tid >> 3)) * K + scol * 8;
    u16* asd = As + wid * 512;
    u16* bsd = Bs + wid * 512;
    const long rs32 = 32L * K;

    f32x4 acc[4][4] = {};
    f32x4 acc_l[4] = {};
    const short8 ones8 = {16256, 16256, 16256, 16256, 16256, 16256, 16256, 16256};
    const int fr = lane & 15, fq = lane >> 4;
    const int sw = (fq ^ (fr & 7)) * 8;
    const int offA0 = (wm + fr) * 64 + sw;
    const int offA1 = offA0 ^ 32;
    const int offB0 = (wn + fr) * 64 + sw;
    const int offB1 = offB0 ^ 32;

    for (int k0 = 0; k0 < K; k0 += 64) {
#pragma unroll
        for (int rd = 0; rd < 4; rd++) {
            load_lds16(ap + k0 + rd * rs32, asd + rd * 2048);
            load_lds16(bp + k0 + rd * rs32, bsd + rd * 2048);
        }
        __syncthreads();
#pragma unroll
        for (int s = 0; s < 2; s++) {
            const int oa = s ? offA1 : offA0;
            const int ob = s ? offB1 : offB0;
            short8 b0 = *(const short8*)&Bs[ob];
            short8 b1 = *(const short8*)&Bs[ob + 1024];
            short8 b2 = *(const short8*)&Bs[ob + 2048];
            short8 b3 = *(const short8*)&Bs[ob + 3072];
#pragma unroll
            for (int i = 0; i < 4; i++) {
                const short8 a = *(const short8*)&As[oa + i * 1024];
                acc[i][0] = __builtin_amdgcn_mfma_f32_16x16x32_bf16(a, b0, acc[i][0], 0, 0, 0);
                acc[i][1] = __builtin_amdgcn_mfma_f32_16x16x32_bf16(a, b1, acc[i][1], 0, 0, 0);
                acc[i][2] = __builtin_amdgcn_mfma_f32_16x16x32_bf16(a, b2, acc[i][2], 0, 0, 0);
                acc[i][3] = __builtin_amdgcn_mfma_f32_16x16x32_bf16(a, b3, acc[i][3], 0, 0, 0);
                if (MODE == 3)
                    acc_l[i] = __builtin_amdgcn_mfma_f32_16x16x32_bf16(a, ones8, acc_l[i], 0, 0, 0);
            }
        }
        __syncthreads();
    }

    const int cn = lane & 15;
    const int cm = (lane >> 4) * 4;
    float invl[4][4];
    if (MODE == 3) {
#pragma unroll
        for (int i = 0; i < 4; i++)
#pragma unroll
            for (int r = 0; r < 4; r++) invl[i][r] = 1.0f / acc_l[i][r];
    }
#pragma unroll
    for (int i = 0; i < 4; i++) {
        const int gmb = m0 + wm + i * 16 + cm;
#pragma unroll
        for (int j = 0; j < 4; j++) {
            const int gn = n0 + wn + j * 16 + cn;
            const float bv = (MODE <= 1 || MODE == 4) ? bias[gn] : 0.0f;
            if (MODE == 1 || (MODE == 4 && bz == 2)) {
                u16* dst = (MODE == 4) ? (u16*)Cout2 : (u16*)Cout;
                const int batch = gmb >> 11;
                const int jj = gmb & 2047;
                u16 o[4];
#pragma unroll
                for (int r = 0; r < 4; r++) o[r] = f2bf(acc[i][j][r] + bv);
                *(uint2*)(dst + ((long)batch * N + gn) * 2048 + jj) = *(uint2*)o;
            } else if (MODE == 0 || MODE == 4) {
                u16* dst = (u16*)Cout + ((MODE == 4) ? (long)bz * 16777216 : 0);
#pragma unroll
                for (int r = 0; r < 4; r++)
                    dst[(long)(gmb + r) * N + gn] = f2bf(acc[i][j][r] + bv);
            } else {
#pragma unroll
                for (int r = 0; r < 4; r++) {
                    const long gm = gmb + r;
                    float v = acc[i][j][r];
                    if (MODE == 2) v = __expf(v * scale);
                    if (MODE == 3)
                        ((float*)Cout)[(long)bz * sC + gm * N + gn] = v * invl[i][r];
                    else
                        ((u16*)Cout)[(long)bz * sC + gm * N + gn] = f2bf(v);
                }
            }
        }
    }
}

// ================= 256x256 8-phase counted-vmcnt GEMM (r8) =================
// BM=BN=256, BK=64, 512 thr = 8 waves (4M x 2N), per-wave out 64x128.
// LDS 128 KiB: Ar0/Ar1/Br0/Br1 = 256x64 bf16 each, XOR-swizzled.
// r8 hardening vs r7: every mid-phase barrier is lgkmcnt(0)-gated, so all
// ds_reads issued before a barrier are COMPLETE when any wave passes it.
// Every stage (global_load_lds) into a region is issued >=1 lgkm-gated
// barrier after that region's last ds_read -> read/overwrite race is
// provably closed. Counted vmcnt(4) only at P4/P8 (2 half-tiles in flight
// across barriers); accounting: at P4-end drain retires tile t1 (A+B), at
// P8-end retires t2, leaving exactly the 4 odd-tile A loads in flight.
__device__ __forceinline__ void pbar() {
    __builtin_amdgcn_sched_barrier(0);
    asm volatile("" ::: "memory");
    __builtin_amdgcn_s_barrier();
    asm volatile("" ::: "memory");
    __builtin_amdgcn_sched_barrier(0);
}

// mid-phase barrier: force this wave's ds_reads complete, then barrier
__device__ __forceinline__ void bar_lgkm() {
    __builtin_amdgcn_sched_barrier(0);
    asm volatile("s_waitcnt lgkmcnt(0)" ::: "memory");
    __builtin_amdgcn_sched_barrier(0);
    __builtin_amdgcn_s_barrier();
    asm volatile("" ::: "memory");
    __builtin_amdgcn_sched_barrier(0);
}

#define RDA4(dst, reg, off) do { \
    dst[0] = *(const short8*)&(reg)[(off)];        \
    dst[1] = *(const short8*)&(reg)[(off) + 1024]; \
    dst[2] = *(const short8*)&(reg)[(off) + 2048]; \
    dst[3] = *(const short8*)&(reg)[(off) + 3072]; } while (0)

#define RDB8(dst, reg, off) do { \
    dst[0] = *(const short8*)&(reg)[(off)];        \
    dst[1] = *(const short8*)&(reg)[(off) + 1024]; \
    dst[2] = *(const short8*)&(reg)[(off) + 2048]; \
    dst[3] = *(const short8*)&(reg)[(off) + 3072]; \
    dst[4] = *(const short8*)&(reg)[(off) + 4096]; \
    dst[5] = *(const short8*)&(reg)[(off) + 5120]; \
    dst[6] = *(const short8*)&(reg)[(off) + 6144]; \
    dst[7] = *(const short8*)&(reg)[(off) + 7168]; } while (0)

#define MM16(af, bf, JL) do { \
    __builtin_amdgcn_s_setprio(1); \
    _Pragma("unroll") \
    for (int i_ = 0; i_ < 4; i_++) { \
        _Pragma("unroll") \
        for (int j_ = 0; j_ < 4; j_++) \
            acc[i_][(JL) + j_] = __builtin_amdgcn_mfma_f32_16x16x32_bf16( \
                af[i_], bf[(JL) + j_], acc[i_][(JL) + j_], 0, 0, 0); \
    } \
    __builtin_amdgcn_s_setprio(0); } while (0)

#define STA(reg, hm, kt) do { \
    const u16* s_ = apg + (hm) * rH + (long)(kt) * 64; \
    u16* d_ = (reg) + (hm) * 8192 + w * 1024; \
    load_lds16(s_, d_); \
    load_lds16(s_ + rK8, d_ + 512); } while (0)

#define STB(reg, hm, kt) do { \
    const u16* s_ = bpg + (hm) * rH + (long)(kt) * 64; \
    u16* d_ = (reg) + (hm) * 8192 + w * 1024; \
    load_lds16(s_, d_); \
    load_lds16(s_ + rK8, d_ + 512); } while (0)

// MODE 2: bf16 out = exp(acc*scale), per-batch grid decode (batch = XCD)
// MODE 4: merged QKV, grid(M/256, N/256, 3); z<2 row-major +bias, z=2 vT
template<int MODE>
__global__ __launch_bounds__(512, 2)
void gemm8(const u16* __restrict__ A, const u16* __restrict__ B,
           const float* __restrict__ bias0, const float* __restrict__ bias1,
           const float* __restrict__ bias2,
           void* __restrict__ Cout, void* __restrict__ Cout2,
           const int M, const int N, const int K, const float scale,
           const long sA, const long sB, const long sC)
{
    int bz, m0, n0;
    if (MODE == 2) {
        const int id = blockIdx.x;
        bz = id & 7;                      // one batch per XCD
        m0 = ((id >> 3) & 7) * 256;
        n0 = (id >> 6) * 256;
    } else {
        bz = blockIdx.z;
        m0 = blockIdx.x * 256;
        n0 = blockIdx.y * 256;
    }
    A += (long)bz * sA;
    B += (long)bz * sB;
    const float* bias = (MODE == 4) ? (bz == 0 ? bias0 : bz == 1 ? bias1 : bias2)
                                    : bias0;

    __shared__ __align__(16) u16 lds[65536];   // 128 KiB
    u16* const Ar0 = lds;
    u16* const Ar1 = lds + 16384;
    u16* const Br0 = lds + 32768;
    u16* const Br1 = lds + 49152;

    const int tid = threadIdx.x;
    const int w = tid >> 6, l = tid & 63;
    // staging: wave w covers rows w*16 + (l>>3) (+8 for 2nd load) of a
    // 128-row half; global col-group pre-swizzled so the linear LDS fill
    // (wave-uniform base + lane*16B) realizes the swizzled layout:
    // LDS[r*64 + ((cg ^ (r&7))*8)] = global cols cg*8..cg*8+7 of row r.
    const int cgrp = (l & 7) ^ ((l >> 3) & 7);
    const long rK8 = 8L * K;
    const long rH  = 128L * K;
    const u16* apg = A + (long)(m0 + w * 16 + (l >> 3)) * K + cgrp * 8;
    const u16* bpg = B + (long)(n0 + w * 16 + (l >> 3)) * K + cgrp * 8;

    const int wm = (w & 3) * 64;          // 4 waves along M
    const int wn = (w >> 2) * 128;        // 2 waves along N
    const int fr = l & 15, fq = l >> 4;
    const int sw8 = (fq ^ (fr & 7)) * 8;
    const int offA = (wm + fr) * 64 + sw8;   // +i*1024 per m-tile, ^32 for s=1
    const int offB = (wn + fr) * 64 + sw8;   // +j*1024 per n-tile

    f32x4 acc[4][8] = {};
    short8 aA0[4], aA1e[4], aA1o[4] = {};
    short8 bB0[8], bB1[8] = {};

    // prologue: tile0 (A,B) -> buf0; tile1 A-halves -> buf1  (6 half-tiles)
    STA(Ar0, 0, 0); STA(Ar0, 1, 0);
    STB(Br0, 0, 0); STB(Br0, 1, 0);
    STA(Ar1, 0, 1); STA(Ar1, 1, 1);
    __builtin_amdgcn_sched_barrier(0);
    asm volatile("s_waitcnt vmcnt(4)" ::: "memory");   // tile0 landed
    __builtin_amdgcn_s_barrier();
    asm volatile("" ::: "memory");
    __builtin_amdgcn_sched_barrier(0);

    const int NI = K >> 7;                // 2 K-tiles per iteration
    for (int it = 0; it < NI; ++it) {
        const bool nl = (it < NI - 1);
        const int t1 = 2 * it + 1, t2 = 2 * it + 2, t3 = 2 * it + 3;
        // P1: read buf0 A s0; stage B-h0(t1)->Br1; MFMA prev-odd s1 lo (0 on it=0)
        RDA4(aA0, Ar0, offA);
        STB(Br1, 0, t1);
        bar_lgkm();
        MM16(aA1o, bB1, 0);
        pbar();
        // P2: read buf0 A s1; stage B-h1(t1)->Br1; MFMA prev-odd s1 hi
        RDA4(aA1e, Ar0, offA ^ 32);
        STB(Br1, 1, t1);
        bar_lgkm();
        MM16(aA1o, bB1, 4);
        pbar();
        // P3: read buf0 B s0; stage A-h0(t2)->Ar0; MFMA even s0 lo
        RDB8(bB0, Br0, offB);
        if (nl) STA(Ar0, 0, t2);
        bar_lgkm();
        MM16(aA0, bB0, 0);
        pbar();
        // P4: read buf0 B s1; stage A-h1(t2)->Ar0; MFMA even s0 hi; vmcnt
        RDB8(bB1, Br0, offB ^ 32);
        if (nl) STA(Ar0, 1, t2);
        bar_lgkm();
        MM16(aA0, bB0, 4);
        __builtin_amdgcn_sched_barrier(0);
        asm volatile("" ::: "memory");
        if (nl) asm volatile("s_waitcnt vmcnt(4)" ::: "memory");  // t1 complete
        else    asm volatile("s_waitcnt vmcnt(0)" ::: "memory");  // final drain
        __builtin_amdgcn_s_barrier();
        asm volatile("" ::: "memory");
        __builtin_amdgcn_sched_barrier(0);
        // P5: read buf1 A s0; stage B-h0(t2)->Br0; MFMA even s1 lo
        RDA4(aA0, Ar1, offA);
        if (nl) STB(Br0, 0, t2);
        bar_lgkm();
        MM16(aA1e, bB1, 0);
        pbar();
        // P6: read buf1 A s1; stage B-h1(t2)->Br0; MFMA even s1 hi
        RDA4(aA1o, Ar1, offA ^ 32);
        if (nl) STB(Br0, 1, t2);
        bar_lgkm();
        MM16(aA1e, bB1, 4);
        pbar();
        // P7: read buf1 B s0; stage A-h0(t3)->Ar1; MFMA odd s0 lo
        RDB8(bB0, Br1, offB);
        if (nl) STA(Ar1, 0, t3);
        bar_lgkm();
        MM16(aA0, bB0, 0);
        pbar();
        // P8: read buf1 B s1; stage A-h1(t3)->Ar1; MFMA odd s0 hi; vmcnt
        RDB8(bB1, Br1, offB ^ 32);
        if (nl) STA(Ar1, 1, t3);
        bar_lgkm();
        MM16(aA0, bB0, 4);
        __builtin_amdgcn_sched_barrier(0);
        asm volatile("" ::: "memory");
        asm volatile("s_waitcnt vmcnt(4)" ::: "memory");          // t2 complete
        __builtin_amdgcn_s_barrier();
        asm volatile("" ::: "memory");
        __builtin_amdgcn_sched_barrier(0);
    }
    // drain: last odd tile s1 (operands read at P6/P8 of final iteration)
    MM16(aA1o, bB1, 0);
    MM16(aA1o, bB1, 4);

    // epilogue: C/D layout col=lane&15, row=(lane>>4)*4+r
    const int cn = l & 15, cm = (l >> 4) * 4;
#pragma unroll
    for (int i = 0; i < 4; i++) {
        const int gmb = m0 + wm + i * 16 + cm;
#pragma unroll
        for (int j = 0; j < 8; j++) {
            const int gn = n0 + wn + j * 16 + cn;
            if (MODE == 4) {
                const float bv = bias[gn];
                if (bz == 2) {
                    const int batch = gmb >> 11, jj = gmb & 2047;
                    u16 o[4];
#pragma unroll
                    for (int r = 0; r < 4; r++) o[r] = f2bf(acc[i][j][r] + bv);
                    *(uint2*)((u16*)Cout2 + ((long)batch * N + gn) * 2048 + jj) = *(uint2*)o;
                } else {
                    u16* dst = (u16*)Cout + (long)bz * ((long)M * N);
#pragma unroll
                    for (int r = 0; r < 4; r++)
                        dst[(long)(gmb + r) * N + gn] = f2bf(acc[i][j][r] + bv);
                }
            } else {
#pragma unroll
                for (int r = 0; r < 4; r++)
                    ((u16*)Cout)[(long)bz * sC + (long)(gmb + r) * N + gn] =
                        f2bf(__expf(acc[i][j][r] * scale));
            }
        }
    }
}

extern "C" void kernel_launch(void* const* d_in, const int* in_sizes, int n_in,
                              void* d_out, int out_size, void* d_ws, size_t ws_size,
                              hipStream_t stream) {
    const float* target = (const float*)d_in[0];
    const float* src_k  = (const float*)d_in[1];
    const float* src_v  = (const float*)d_in[2];
    const float* Wq = (const float*)d_in[3];
    const float* bq = (const float*)d_in[4];
    const float* Wk = (const float*)d_in[5];
    const float* bk = (const float*)d_in[6];
    const float* Wv = (const float*)d_in[7];
    const float* bv = (const float*)d_in[8];
    const float* g_t = (const float*)d_in[9];
    const float* b_t = (const float*)d_in[10];
    const float* g_k = (const float*)d_in[11];
    const float* b_k = (const float*)d_in[12];
    const float* g_v = (const float*)d_in[13];
    const float* b_v = (const float*)d_in[14];

    char* ws = (char*)d_ws;
    const float scale = 0.03125f;  // 1024^-0.5
    const size_t MB = 1048576;

    if (ws_size >= 198 * MB) {
        // merged path: peak 198 MB
        u16* q   = (u16*)(ws + 0);            // 16384x1024 bf16 (q,kk contiguous)
        u16* kk  = (u16*)(ws + 32 * MB);
        u16* vT  = (u16*)(ws + 64 * MB);      // 8 x 1024 x 2048 bf16
        u16* ln3 = (u16*)(ws + 96 * MB);      // 3 x 16384x1024 bf16 (dead after proj)
        u16* wqb = (u16*)(ws + 192 * MB);     // 3 x 1024x1024 bf16
        u16* S   = (u16*)(ws + 96 * MB);      // 8x2048x2048 bf16 (aliases ln3)

        cast3_kernel<<<3072, 256, 0, stream>>>(Wq, Wk, Wv, wqb);
        ln3_kernel<<<49152, 256, 0, stream>>>(target, src_k, src_v,
                                              g_t, g_k, g_v, b_t, b_k, b_v, ln3);
        // Q/K/V projections: 256^2 8-phase kernel, one dispatch (z = projection)
        gemm8<4><<<dim3(64, 4, 3), 512, 0, stream>>>(ln3, wqb, bq, bk, bv,
            q, vT, 16384, 1024, 1024, 1.0f, 16777216L, 1048576L, 0);
        // P[b] = exp((q[b] @ k[b]^T) * scale): 256^2 8-phase
        gemm8<2><<<512, 512, 0, stream>>>(q, kk, nullptr, nullptr, nullptr, S, nullptr,
            2048, 2048, 1024, scale, 2048L * 1024, 2048L * 1024, 2048L * 2048);
        // out[b] = (P[b] @ vT[b]^T) / rowsum(P[b])  (old kernel; port next round)
        gemm_bt<3><<<1024, 256, 0, stream>>>(S, vT, nullptr, nullptr, nullptr, d_out, nullptr,
            2048, 1024, 2048, 1.0f, 2048L * 2048, 1024L * 2048, 2048L * 1024);
    } else {
        // fallback (r6) path: peak ~140.5 MB
        u16* q   = (u16*)(ws + 0);
        u16* kk  = (u16*)(ws + 32 * MB);
        u16* vT  = (u16*)(ws + 64 * MB);
        u16* ln  = (u16*)(ws + 96 * MB);
        u16* wqb = (u16*)(ws + 128 * MB);
        u16* wkb = wqb + 1048576;
        u16* wvb = wkb + 1048576;
        u16* S   = (u16*)(ws + 96 * MB);

        cast3_kernel<<<3072, 256, 0, stream>>>(Wq, Wk, Wv, wqb);
        ln_cast_kernel<<<16384, 256, 0, stream>>>(target, g_t, b_t, ln);
        gemm_bt<0><<<dim3(128, 8, 1), 256, 0, stream>>>(ln, wqb, bq, nullptr, nullptr,
            q, nullptr, 16384, 1024, 1024, 1.0f, 0, 0, 0);
        ln_cast_kernel<<<16384, 256, 0, stream>>>(src_k, g_k, b_k, ln);
        gemm_bt<0><<<dim3(128, 8, 1), 256, 0, stream>>>(ln, wkb, bk, nullptr, nullptr,
            kk, nullptr, 16384, 1024, 1024, 1.0f, 0, 0, 0);
        ln_cast_kernel<<<16384, 256, 0, stream>>>(src_v, g_v, b_v, ln);
        gemm_bt<1><<<dim3(128, 8, 1), 256, 0, stream>>>(ln, wvb, bv, nullptr, nullptr,
            vT, nullptr, 16384, 1024, 1024, 1.0f, 0, 0, 0);
        gemm_bt<2><<<2048, 256, 0, stream>>>(q, kk, nullptr, nullptr, nullptr, S, nullptr,
            2048, 2048, 1024, scale, 2048L * 1024, 2048L * 1024, 2048L * 2048);
        gemm_bt<3><<<1024, 256, 0, stream>>>(S, vT, nullptr, nullptr, nullptr, d_out, nullptr,
            2048, 1024, 2048, 1.0f, 2048L * 2048, 1024L * 2048, 2048L * 1024);
    }
}

// Round 3
// 522.125 us; speedup vs baseline: 2.2063x; 2.2063x over previous
//
#include <hip/hip_runtime.h>
#include <cstdint>

using u16 = unsigned short;
using u32 = unsigned int;
typedef __attribute__((ext_vector_type(8))) short short8;
typedef __attribute__((ext_vector_type(4))) float f32x4;

__device__ __forceinline__ float bf2f(u16 u) { return __uint_as_float(((u32)u) << 16); }
__device__ __forceinline__ u16 f2bf(float f) {
    u32 u = __float_as_uint(f);
    u32 r = u + 0x7fffu + ((u >> 16) & 1u);   // round-to-nearest-even
    return (u16)(r >> 16);
}

__device__ __forceinline__ void load_lds16(const void* g, void* l) {
    __builtin_amdgcn_global_load_lds((const __attribute__((address_space(1))) void*)g,
                                     (__attribute__((address_space(3))) void*)l, 16, 0, 0);
}

// ---------------- LayerNorm row body (1024 fp32 -> bf16) ----------------
__device__ __forceinline__ void ln_row(const float* __restrict__ x,
                                       const float* __restrict__ gw,
                                       const float* __restrict__ bw,
                                       u16* __restrict__ y, int row) {
    const int tid = threadIdx.x;
    const float4 v = ((const float4*)(x + (size_t)row * 1024))[tid];
    float s  = v.x + v.y + v.z + v.w;
    float ss = v.x * v.x + v.y * v.y + v.z * v.z + v.w * v.w;
#pragma unroll
    for (int off = 32; off; off >>= 1) {
        s  += __shfl_xor(s, off);
        ss += __shfl_xor(ss, off);
    }
    __shared__ float sm[8];
    const int lane = tid & 63, wid = tid >> 6;
    if (lane == 0) { sm[wid] = s; sm[wid + 4] = ss; }
    __syncthreads();
    s  = sm[0] + sm[1] + sm[2] + sm[3];
    ss = sm[4] + sm[5] + sm[6] + sm[7];
    const float mu   = s * (1.0f / 1024.0f);
    const float var  = ss * (1.0f / 1024.0f) - mu * mu;
    const float rstd = rsqrtf(var + 1e-5f);
    const float4 g4 = ((const float4*)gw)[tid];
    const float4 b4 = ((const float4*)bw)[tid];
    u16 o[4];
    o[0] = f2bf((v.x - mu) * rstd * g4.x + b4.x);
    o[1] = f2bf((v.y - mu) * rstd * g4.y + b4.y);
    o[2] = f2bf((v.z - mu) * rstd * g4.z + b4.z);
    o[3] = f2bf((v.w - mu) * rstd * g4.w + b4.w);
    *(uint2*)(y + (size_t)row * 1024 + tid * 4) = *(uint2*)o;
}

__global__ __launch_bounds__(256)
void ln_cast_kernel(const float* __restrict__ x, const float* __restrict__ gw,
                    const float* __restrict__ bw, u16* __restrict__ y) {
    ln_row(x, gw, bw, y, blockIdx.x);
}

// merged: all 3 layernorms in one dispatch (sel = bid>>14)
__global__ __launch_bounds__(256)
void ln3_kernel(const float* __restrict__ x0, const float* __restrict__ x1,
                const float* __restrict__ x2,
                const float* __restrict__ g0, const float* __restrict__ g1,
                const float* __restrict__ g2,
                const float* __restrict__ b0, const float* __restrict__ b1,
                const float* __restrict__ b2, u16* __restrict__ y) {
    const int bid = blockIdx.x;
    const int sel = bid >> 14;
    const int row = bid & 16383;
    const float* x  = (sel == 0) ? x0 : (sel == 1) ? x1 : x2;
    const float* gw = (sel == 0) ? g0 : (sel == 1) ? g1 : g2;
    const float* bw = (sel == 0) ? b0 : (sel == 1) ? b1 : b2;
    ln_row(x, gw, bw, y + ((size_t)sel << 24), row);
}

// ---------------- fp32 -> bf16 cast of the 3 weight matrices ----------------
__global__ __launch_bounds__(256)
void cast3_kernel(const float* __restrict__ wa, const float* __restrict__ wb,
                  const float* __restrict__ wc, u16* __restrict__ oa) {
    const int bid = blockIdx.x;
    const int sel = bid >> 10;
    const float* s = (sel == 0) ? wa : (sel == 1) ? wb : wc;
    u16* d = oa + (size_t)sel * 1048576;
    const int i = (bid & 1023) * 256 + threadIdx.x;
    const float4 v = ((const float4*)s)[i];
    u16 o[4] = { f2bf(v.x), f2bf(v.y), f2bf(v.z), f2bf(v.w) };
    *(uint2*)(d + (size_t)i * 4) = *(uint2*)o;
}

// ---------------- old 128x128 GEMM (kept for MODE 3 / fallback) -----------
template<int MODE>
__global__ __launch_bounds__(256, (MODE == 3 ? 3 : 4))
void gemm_bt(const u16* __restrict__ A, const u16* __restrict__ B,
             const float* __restrict__ bias0, const float* __restrict__ bias1,
             const float* __restrict__ bias2,
             void* __restrict__ Cout, void* __restrict__ Cout2,
             const int M, const int N, const int K, const float scale,
             const long sA, const long sB, const long sC)
{
    int bz, m0, n0;
    if (MODE == 2 || MODE == 3) {
        const int id = blockIdx.x;
        bz = id & 7;                      // one batch per XCD
        m0 = ((id >> 3) & 15) * 128;
        n0 = (id >> 7) * 128;
    } else {
        bz = (MODE == 4) ? blockIdx.z : 0;
        m0 = blockIdx.x * 128;
        n0 = blockIdx.y * 128;
    }
    A += (long)bz * sA;
    B += (long)bz * sB;
    const float* bias = (MODE == 4) ? (bz == 0 ? bias0 : bz == 1 ? bias1 : bias2)
                                    : bias0;
    __shared__ __align__(16) u16 As[128 * 64];
    __shared__ __align__(16) u16 Bs[128 * 64];
    const int tid  = threadIdx.x;
    const int lane = tid & 63, wid = tid >> 6;
    const int wm = (wid & 1) * 64, wn = (wid >> 1) * 64;

    const int scol = (tid & 7) ^ ((tid >> 3) & 7);
    const u16* ap = A + (long)(m0 + (tid >> 3)) * K + scol * 8;
    const u16* bp = B + (long)(n0 + (tid >> 3)) * K + scol * 8;
    u16* asd = As + wid * 512;
    u16* bsd = Bs + wid * 512;
    const long rs32 = 32L * K;

    f32x4 acc[4][4] = {};
    f32x4 acc_l[4] = {};
    const short8 ones8 = {16256, 16256, 16256, 16256, 16256, 16256, 16256, 16256};
    const int fr = lane & 15, fq = lane >> 4;
    const int sw = (fq ^ (fr & 7)) * 8;
    const int offA0 = (wm + fr) * 64 + sw;
    const int offA1 = offA0 ^ 32;
    const int offB0 = (wn + fr) * 64 + sw;
    const int offB1 = offB0 ^ 32;

    for (int k0 = 0; k0 < K; k0 += 64) {
#pragma unroll
        for (int rd = 0; rd < 4; rd++) {
            load_lds16(ap + k0 + rd * rs32, asd + rd * 2048);
            load_lds16(bp + k0 + rd * rs32, bsd + rd * 2048);
        }
        __syncthreads();
#pragma unroll
        for (int s = 0; s < 2; s++) {
            const int oa = s ? offA1 : offA0;
            const int ob = s ? offB1 : offB0;
            short8 b0 = *(const short8*)&Bs[ob];
            short8 b1 = *(const short8*)&Bs[ob + 1024];
            short8 b2 = *(const short8*)&Bs[ob + 2048];
            short8 b3 = *(const short8*)&Bs[ob + 3072];
#pragma unroll
            for (int i = 0; i < 4; i++) {
                const short8 a = *(const short8*)&As[oa + i * 1024];
                acc[i][0] = __builtin_amdgcn_mfma_f32_16x16x32_bf16(a, b0, acc[i][0], 0, 0, 0);
                acc[i][1] = __builtin_amdgcn_mfma_f32_16x16x32_bf16(a, b1, acc[i][1], 0, 0, 0);
                acc[i][2] = __builtin_amdgcn_mfma_f32_16x16x32_bf16(a, b2, acc[i][2], 0, 0, 0);
                acc[i][3] = __builtin_amdgcn_mfma_f32_16x16x32_bf16(a, b3, acc[i][3], 0, 0, 0);
                if (MODE == 3)
                    acc_l[i] = __builtin_amdgcn_mfma_f32_16x16x32_bf16(a, ones8, acc_l[i], 0, 0, 0);
            }
        }
        __syncthreads();
    }

    const int cn = lane & 15;
    const int cm = (lane >> 4) * 4;
    float invl[4][4];
    if (MODE == 3) {
#pragma unroll
        for (int i = 0; i < 4; i++)
#pragma unroll
            for (int r = 0; r < 4; r++) invl[i][r] = 1.0f / acc_l[i][r];
    }
#pragma unroll
    for (int i = 0; i < 4; i++) {
        const int gmb = m0 + wm + i * 16 + cm;
#pragma unroll
        for (int j = 0; j < 4; j++) {
            const int gn = n0 + wn + j * 16 + cn;
            const float bv = (MODE <= 1 || MODE == 4) ? bias[gn] : 0.0f;
            if (MODE == 1 || (MODE == 4 && bz == 2)) {
                u16* dst = (MODE == 4) ? (u16*)Cout2 : (u16*)Cout;
                const int batch = gmb >> 11;
                const int jj = gmb & 2047;
                u16 o[4];
#pragma unroll
                for (int r = 0; r < 4; r++) o[r] = f2bf(acc[i][j][r] + bv);
                *(uint2*)(dst + ((long)batch * N + gn) * 2048 + jj) = *(uint2*)o;
            } else if (MODE == 0 || MODE == 4) {
                u16* dst = (u16*)Cout + ((MODE == 4) ? (long)bz * 16777216 : 0);
#pragma unroll
                for (int r = 0; r < 4; r++)
                    dst[(long)(gmb + r) * N + gn] = f2bf(acc[i][j][r] + bv);
            } else {
#pragma unroll
                for (int r = 0; r < 4; r++) {
                    const long gm = gmb + r;
                    float v = acc[i][j][r];
                    if (MODE == 2) v = __expf(v * scale);
                    if (MODE == 3)
                        ((float*)Cout)[(long)bz * sC + gm * N + gn] = v * invl[i][r];
                    else
                        ((u16*)Cout)[(long)bz * sC + gm * N + gn] = f2bf(v);
                }
            }
        }
    }
}

// ================= 256x256 8-phase quadrant GEMM (r9) =====================
// r8 post-mortem: __launch_bounds__(512,2) = 2 blocks/CU (CUDA semantics) ->
// 128-VGPR cap -> acc spilled to scratch (FETCH+WRITE ~1 GB/dispatch, 8% Mfma).
// r9: (a) __launch_bounds__(512,1) -> 256-VGPR budget (LDS caps at 1 block/CU
// anyway); (b) m201 quadrant-phase structure to cut live regs to ~210:
//   waves 2M x 4N, per-wave 128x64 out, acc[8][4] (128 VGPR).
//   Phase = 16 MFMA on one C-quadrant (mh,nh) over full K=64.
//   Operands: ONE reusable A-half aF[8] (32 VGPR) + bF0[4] + bF1[4] (32 VGPR).
// Phases/K-tile: Q00(rd A-h0,B-h0) Q01(rd B-h1) Q10(rd A-h1) Q11(no rd).
// LDS region lifetimes (staging halves): A-halves last read P3 -> stage A @P4;
// B-halves last read P2 -> stage B @P3. vmcnt(8) gates at P4/P8 retire exactly
// the previous tile's 8 loads (order: B4,A4 per tile). Per-acc K-order (tile t:
// s0 then s1, tiles ascending) identical to gemm_bt -> same numerics as r8.
__device__ __forceinline__ void pbar() {
    __builtin_amdgcn_sched_barrier(0);
    asm volatile("" ::: "memory");
    __builtin_amdgcn_s_barrier();
    asm volatile("" ::: "memory");
    __builtin_amdgcn_sched_barrier(0);
}

// pre-MFMA barrier: this wave's ds_reads complete, then block barrier
__device__ __forceinline__ void bar_lgkm() {
    __builtin_amdgcn_sched_barrier(0);
    asm volatile("s_waitcnt lgkmcnt(0)" ::: "memory");
    __builtin_amdgcn_sched_barrier(0);
    __builtin_amdgcn_s_barrier();
    asm volatile("" ::: "memory");
    __builtin_amdgcn_sched_barrier(0);
}

// A-half: 4 m-tiles x 2 k-slices (8 x ds_read_b128)
#define RDAH(reg, mh) do { \
    aF[0] = *(const short8*)&(reg)[ offA + ((mh)*4+0)*1024];        \
    aF[1] = *(const short8*)&(reg)[(offA + ((mh)*4+0)*1024) ^ 32];  \
    aF[2] = *(const short8*)&(reg)[ offA + ((mh)*4+1)*1024];        \
    aF[3] = *(const short8*)&(reg)[(offA + ((mh)*4+1)*1024) ^ 32];  \
    aF[4] = *(const short8*)&(reg)[ offA + ((mh)*4+2)*1024];        \
    aF[5] = *(const short8*)&(reg)[(offA + ((mh)*4+2)*1024) ^ 32];  \
    aF[6] = *(const short8*)&(reg)[ offA + ((mh)*4+3)*1024];        \
    aF[7] = *(const short8*)&(reg)[(offA + ((mh)*4+3)*1024) ^ 32];  } while (0)

// B-half: 2 n-tiles x 2 k-slices (4 x ds_read_b128)
#define RDBH(dst, reg, nh) do { \
    dst[0] = *(const short8*)&(reg)[ offB + ((nh)*2+0)*1024];        \
    dst[1] = *(const short8*)&(reg)[(offB + ((nh)*2+0)*1024) ^ 32];  \
    dst[2] = *(const short8*)&(reg)[ offB + ((nh)*2+1)*1024];        \
    dst[3] = *(const short8*)&(reg)[(offB + ((nh)*2+1)*1024) ^ 32];  } while (0)

// one C-quadrant x K=64: 16 MFMA; per-acc order s0 then s1
#define MMQ(mh, nh, bF) do { \
    __builtin_amdgcn_s_setprio(1); \
    _Pragma("unroll") \
    for (int i_ = 0; i_ < 4; i_++) { \
        _Pragma("unroll") \
        for (int j_ = 0; j_ < 2; j_++) { \
            acc[(mh)*4+i_][(nh)*2+j_] = __builtin_amdgcn_mfma_f32_16x16x32_bf16( \
                aF[2*i_],   bF[2*j_],   acc[(mh)*4+i_][(nh)*2+j_], 0, 0, 0); \
            acc[(mh)*4+i_][(nh)*2+j_] = __builtin_amdgcn_mfma_f32_16x16x32_bf16( \
                aF[2*i_+1], bF[2*j_+1], acc[(mh)*4+i_][(nh)*2+j_], 0, 0, 0); \
        } \
    } \
    __builtin_amdgcn_s_setprio(0); } while (0)

#define STA(reg, hm, kt) do { \
    const u16* s_ = apg + (hm) * rH + (long)(kt) * 64; \
    u16* d_ = (reg) + (hm) * 8192 + w * 1024; \
    load_lds16(s_, d_); \
    load_lds16(s_ + rK8, d_ + 512); } while (0)

#define STB(reg, hm, kt) do { \
    const u16* s_ = bpg + (hm) * rH + (long)(kt) * 64; \
    u16* d_ = (reg) + (hm) * 8192 + w * 1024; \
    load_lds16(s_, d_); \
    load_lds16(s_ + rK8, d_ + 512); } while (0)

// MODE 2: bf16 out = exp(acc*scale), per-batch grid decode (batch = XCD)
// MODE 4: merged QKV, grid(M/256, N/256, 3); z<2 row-major +bias, z=2 vT
template<int MODE>
__global__ __launch_bounds__(512, 1)
void gemm8(const u16* __restrict__ A, const u16* __restrict__ B,
           const float* __restrict__ bias0, const float* __restrict__ bias1,
           const float* __restrict__ bias2,
           void* __restrict__ Cout, void* __restrict__ Cout2,
           const int M, const int N, const int K, const float scale,
           const long sA, const long sB, const long sC)
{
    int bz, m0, n0;
    if (MODE == 2) {
        const int id = blockIdx.x;
        bz = id & 7;                      // one batch per XCD
        m0 = ((id >> 3) & 7) * 256;
        n0 = (id >> 6) * 256;
    } else {
        bz = blockIdx.z;
        m0 = blockIdx.x * 256;
        n0 = blockIdx.y * 256;
    }
    A += (long)bz * sA;
    B += (long)bz * sB;
    const float* bias = (MODE == 4) ? (bz == 0 ? bias0 : bz == 1 ? bias1 : bias2)
                                    : bias0;

    __shared__ __align__(16) u16 lds[65536];   // 128 KiB
    u16* const Ar0 = lds;
    u16* const Ar1 = lds + 16384;
    u16* const Br0 = lds + 32768;
    u16* const Br1 = lds + 49152;

    const int tid = threadIdx.x;
    const int w = tid >> 6, l = tid & 63;
    // staging: wave w covers rows w*16 + (l>>3) (+8 for 2nd load) of a
    // 128-row half; global col-group pre-swizzled so the linear LDS fill
    // realizes LDS[r*64 + ((cg ^ (r&7))*8)] = global cols cg*8.. of row r.
    const int cgrp = (l & 7) ^ ((l >> 3) & 7);
    const long rK8 = 8L * K;
    const long rH  = 128L * K;
    const u16* apg = A + (long)(m0 + w * 16 + (l >> 3)) * K + cgrp * 8;
    const u16* bpg = B + (long)(n0 + w * 16 + (l >> 3)) * K + cgrp * 8;

    const int wm = (w & 1) * 128;         // 2 waves along M (per-wave 128 rows)
    const int wn = (w >> 1) * 64;         // 4 waves along N (per-wave 64 cols)
    const int fr = l & 15, fq = l >> 4;
    const int sw8 = (fq ^ (fr & 7)) * 8;
    const int offA = (wm + fr) * 64 + sw8;   // +i*1024 per m-tile, ^32 for s=1
    const int offB = (wn + fr) * 64 + sw8;   // +j*1024 per n-tile

    f32x4 acc[8][4] = {};
    short8 aF[8];
    short8 bF0[4], bF1[4];

    // prologue: tile0 -> buf0, tile1 -> buf1 (B-halves then A-halves each)
    STB(Br0, 0, 0); STB(Br0, 1, 0); STA(Ar0, 0, 0); STA(Ar0, 1, 0);
    STB(Br1, 0, 1); STB(Br1, 1, 1); STA(Ar1, 0, 1); STA(Ar1, 1, 1);
    __builtin_amdgcn_sched_barrier(0);
    asm volatile("s_waitcnt vmcnt(8)" ::: "memory");   // tile0 landed
    __builtin_amdgcn_s_barrier();
    asm volatile("" ::: "memory");
    __builtin_amdgcn_sched_barrier(0);

    const int NI = K >> 7;                // 2 K-tiles per iteration
    for (int it = 0; it < NI; ++it) {
        const bool nl = (it < NI - 1);
        const int t2 = 2 * it + 2, t3 = 2 * it + 3;
        // ---- tile 2it from buf0 ----
        // P1: rd A-h0 (8) + B-h0 (4); MFMA Q00
        RDAH(Ar0, 0); RDBH(bF0, Br0, 0);
        bar_lgkm();
        MMQ(0, 0, bF0);
        pbar();
        // P2: rd B-h1 (4); MFMA Q01
        RDBH(bF1, Br0, 1);
        bar_lgkm();
        MMQ(0, 1, bF1);
        pbar();
        // P3: rd A-h1 (8); stage B(t2) both halves; MFMA Q10
        RDAH(Ar0, 1);
        if (nl) { STB(Br0, 0, t2); STB(Br0, 1, t2); }
        bar_lgkm();
        MMQ(1, 0, bF0);
        pbar();
        // P4: stage A(t2) both halves; MFMA Q11; gate vmcnt -> tile1 landed
        if (nl) { STA(Ar0, 0, t2); STA(Ar0, 1, t2); }
        __builtin_amdgcn_sched_barrier(0);
        MMQ(1, 1, bF1);
        __builtin_amdgcn_sched_barrier(0);
        asm volatile("" ::: "memory");
        if (nl) asm volatile("s_waitcnt vmcnt(8)" ::: "memory");
        else    asm volatile("s_waitcnt vmcnt(0)" ::: "memory");
        __builtin_amdgcn_s_barrier();
        asm volatile("" ::: "memory");
        __builtin_amdgcn_sched_barrier(0);
        // ---- tile 2it+1 from buf1 ----
        // P5: rd A-h0 + B-h0; MFMA Q00
        RDAH(Ar1, 0); RDBH(bF0, Br1, 0);
        bar_lgkm();
        MMQ(0, 0, bF0);
        pbar();
        // P6: rd B-h1; MFMA Q01
        RDBH(bF1, Br1, 1);
        bar_lgkm();
        MMQ(0, 1, bF1);
        pbar();
        // P7: rd A-h1; stage B(t3); MFMA Q10
        RDAH(Ar1, 1);
        if (nl) { STB(Br1, 0, t3); STB(Br1, 1, t3); }
        bar_lgkm();
        MMQ(1, 0, bF0);
        pbar();
        // P8: stage A(t3); MFMA Q11; gate vmcnt -> tile t2 landed
        if (nl) { STA(Ar1, 0, t3); STA(Ar1, 1, t3); }
        __builtin_amdgcn_sched_barrier(0);
        MMQ(1, 1, bF1);
        __builtin_amdgcn_sched_barrier(0);
        asm volatile("" ::: "memory");
        if (nl) asm volatile("s_waitcnt vmcnt(8)" ::: "memory");
        else    asm volatile("s_waitcnt vmcnt(0)" ::: "memory");
        __builtin_amdgcn_s_barrier();
        asm volatile("" ::: "memory");
        __builtin_amdgcn_sched_barrier(0);
    }

    // epilogue: C/D layout col=lane&15, row=(lane>>4)*4+r
    const int cn = l & 15, cm = (l >> 4) * 4;
#pragma unroll
    for (int i = 0; i < 8; i++) {
        const int gmb = m0 + wm + i * 16 + cm;
#pragma unroll
        for (int j = 0; j < 4; j++) {
            const int gn = n0 + wn + j * 16 + cn;
            if (MODE == 4) {
                const float bv = bias[gn];
                if (bz == 2) {
                    const int batch = gmb >> 11, jj = gmb & 2047;
                    u16 o[4];
#pragma unroll
                    for (int r = 0; r < 4; r++) o[r] = f2bf(acc[i][j][r] + bv);
                    *(uint2*)((u16*)Cout2 + ((long)batch * N + gn) * 2048 + jj) = *(uint2*)o;
                } else {
                    u16* dst = (u16*)Cout + (long)bz * ((long)M * N);
#pragma unroll
                    for (int r = 0; r < 4; r++)
                        dst[(long)(gmb + r) * N + gn] = f2bf(acc[i][j][r] + bv);
                }
            } else {
#pragma unroll
                for (int r = 0; r < 4; r++)
                    ((u16*)Cout)[(long)bz * sC + (long)(gmb + r) * N + gn] =
                        f2bf(__expf(acc[i][j][r] * scale));
            }
        }
    }
}

extern "C" void kernel_launch(void* const* d_in, const int* in_sizes, int n_in,
                              void* d_out, int out_size, void* d_ws, size_t ws_size,
                              hipStream_t stream) {
    const float* target = (const float*)d_in[0];
    const float* src_k  = (const float*)d_in[1];
    const float* src_v  = (const float*)d_in[2];
    const float* Wq = (const float*)d_in[3];
    const float* bq = (const float*)d_in[4];
    const float* Wk = (const float*)d_in[5];
    const float* bk = (const float*)d_in[6];
    const float* Wv = (const float*)d_in[7];
    const float* bv = (const float*)d_in[8];
    const float* g_t = (const float*)d_in[9];
    const float* b_t = (const float*)d_in[10];
    const float* g_k = (const float*)d_in[11];
    const float* b_k = (const float*)d_in[12];
    const float* g_v = (const float*)d_in[13];
    const float* b_v = (const float*)d_in[14];

    char* ws = (char*)d_ws;
    const float scale = 0.03125f;  // 1024^-0.5
    const size_t MB = 1048576;

    if (ws_size >= 198 * MB) {
        // merged path: peak 198 MB
        u16* q   = (u16*)(ws + 0);            // 16384x1024 bf16 (q,kk contiguous)
        u16* kk  = (u16*)(ws + 32 * MB);
        u16* vT  = (u16*)(ws + 64 * MB);      // 8 x 1024 x 2048 bf16
        u16* ln3 = (u16*)(ws + 96 * MB);      // 3 x 16384x1024 bf16 (dead after proj)
        u16* wqb = (u16*)(ws + 192 * MB);     // 3 x 1024x1024 bf16
        u16* S   = (u16*)(ws + 96 * MB);      // 8x2048x2048 bf16 (aliases ln3)

        cast3_kernel<<<3072, 256, 0, stream>>>(Wq, Wk, Wv, wqb);
        ln3_kernel<<<49152, 256, 0, stream>>>(target, src_k, src_v,
                                              g_t, g_k, g_v, b_t, b_k, b_v, ln3);
        // Q/K/V projections: 256^2 8-phase kernel, one dispatch (z = projection)
        gemm8<4><<<dim3(64, 4, 3), 512, 0, stream>>>(ln3, wqb, bq, bk, bv,
            q, vT, 16384, 1024, 1024, 1.0f, 16777216L, 1048576L, 0);
        // P[b] = exp((q[b] @ k[b]^T) * scale): 256^2 8-phase
        gemm8<2><<<512, 512, 0, stream>>>(q, kk, nullptr, nullptr, nullptr, S, nullptr,
            2048, 2048, 1024, scale, 2048L * 1024, 2048L * 1024, 2048L * 2048);
        // out[b] = (P[b] @ vT[b]^T) / rowsum(P[b])  (old kernel; port later)
        gemm_bt<3><<<1024, 256, 0, stream>>>(S, vT, nullptr, nullptr, nullptr, d_out, nullptr,
            2048, 1024, 2048, 1.0f, 2048L * 2048, 1024L * 2048, 2048L * 1024);
    } else {
        // fallback (r6) path: peak ~140.5 MB
        u16* q   = (u16*)(ws + 0);
        u16* kk  = (u16*)(ws + 32 * MB);
        u16* vT  = (u16*)(ws + 64 * MB);
        u16* ln  = (u16*)(ws + 96 * MB);
        u16* wqb = (u16*)(ws + 128 * MB);
        u16* wkb = wqb + 1048576;
        u16* wvb = wkb + 1048576;
        u16* S   = (u16*)(ws + 96 * MB);

        cast3_kernel<<<3072, 256, 0, stream>>>(Wq, Wk, Wv, wqb);
        ln_cast_kernel<<<16384, 256, 0, stream>>>(target, g_t, b_t, ln);
        gemm_bt<0><<<dim3(128, 8, 1), 256, 0, stream>>>(ln, wqb, bq, nullptr, nullptr,
            q, nullptr, 16384, 1024, 1024, 1.0f, 0, 0, 0);
        ln_cast_kernel<<<16384, 256, 0, stream>>>(src_k, g_k, b_k, ln);
        gemm_bt<0><<<dim3(128, 8, 1), 256, 0, stream>>>(ln, wkb, bk, nullptr, nullptr,
            kk, nullptr, 16384, 1024, 1024, 1.0f, 0, 0, 0);
        ln_cast_kernel<<<16384, 256, 0, stream>>>(src_v, g_v, b_v, ln);
        gemm_bt<1><<<dim3(128, 8, 1), 256, 0, stream>>>(ln, wvb, bv, nullptr, nullptr,
            vT, nullptr, 16384, 1024, 1024, 1.0f, 0, 0, 0);
        gemm_bt<2><<<2048, 256, 0, stream>>>(q, kk, nullptr, nullptr, nullptr, S, nullptr,
            2048, 2048, 1024, scale, 2048L * 1024, 2048L * 1024, 2048L * 2048);
        gemm_bt<3><<<1024, 256, 0, stream>>>(S, vT, nullptr, nullptr, nullptr, d_out, nullptr,
            2048, 1024, 2048, 1.0f, 2048L * 2048, 1024L * 2048, 2048L * 1024);
    }
}

// Round 4
// 504.865 us; speedup vs baseline: 2.2818x; 1.0342x over previous
//
#include <hip/hip_runtime.h>
#include <cstdint>

using u16 = unsigned short;
using u32 = unsigned int;
typedef __attribute__((ext_vector_type(8))) short short8;
typedef __attribute__((ext_vector_type(4))) float f32x4;

__device__ __forceinline__ float bf2f(u16 u) { return __uint_as_float(((u32)u) << 16); }
__device__ __forceinline__ u16 f2bf(float f) {
    u32 u = __float_as_uint(f);
    u32 r = u + 0x7fffu + ((u >> 16) & 1u);   // round-to-nearest-even
    return (u16)(r >> 16);
}

__device__ __forceinline__ void load_lds16(const void* g, void* l) {
    __builtin_amdgcn_global_load_lds((const __attribute__((address_space(1))) void*)g,
                                     (__attribute__((address_space(3))) void*)l, 16, 0, 0);
}

// ---------------- LayerNorm row body (1024 fp32 -> bf16) ----------------
__device__ __forceinline__ void ln_row(const float* __restrict__ x,
                                       const float* __restrict__ gw,
                                       const float* __restrict__ bw,
                                       u16* __restrict__ y, int row) {
    const int tid = threadIdx.x;
    const float4 v = ((const float4*)(x + (size_t)row * 1024))[tid];
    float s  = v.x + v.y + v.z + v.w;
    float ss = v.x * v.x + v.y * v.y + v.z * v.z + v.w * v.w;
#pragma unroll
    for (int off = 32; off; off >>= 1) {
        s  += __shfl_xor(s, off);
        ss += __shfl_xor(ss, off);
    }
    __shared__ float sm[8];
    const int lane = tid & 63, wid = tid >> 6;
    if (lane == 0) { sm[wid] = s; sm[wid + 4] = ss; }
    __syncthreads();
    s  = sm[0] + sm[1] + sm[2] + sm[3];
    ss = sm[4] + sm[5] + sm[6] + sm[7];
    const float mu   = s * (1.0f / 1024.0f);
    const float var  = ss * (1.0f / 1024.0f) - mu * mu;
    const float rstd = rsqrtf(var + 1e-5f);
    const float4 g4 = ((const float4*)gw)[tid];
    const float4 b4 = ((const float4*)bw)[tid];
    u16 o[4];
    o[0] = f2bf((v.x - mu) * rstd * g4.x + b4.x);
    o[1] = f2bf((v.y - mu) * rstd * g4.y + b4.y);
    o[2] = f2bf((v.z - mu) * rstd * g4.z + b4.z);
    o[3] = f2bf((v.w - mu) * rstd * g4.w + b4.w);
    *(uint2*)(y + (size_t)row * 1024 + tid * 4) = *(uint2*)o;
}

__global__ __launch_bounds__(256)
void ln_cast_kernel(const float* __restrict__ x, const float* __restrict__ gw,
                    const float* __restrict__ bw, u16* __restrict__ y) {
    ln_row(x, gw, bw, y, blockIdx.x);
}

// merged: all 3 layernorms in one dispatch (sel = bid>>14)
__global__ __launch_bounds__(256)
void ln3_kernel(const float* __restrict__ x0, const float* __restrict__ x1,
                const float* __restrict__ x2,
                const float* __restrict__ g0, const float* __restrict__ g1,
                const float* __restrict__ g2,
                const float* __restrict__ b0, const float* __restrict__ b1,
                const float* __restrict__ b2, u16* __restrict__ y) {
    const int bid = blockIdx.x;
    const int sel = bid >> 14;
    const int row = bid & 16383;
    const float* x  = (sel == 0) ? x0 : (sel == 1) ? x1 : x2;
    const float* gw = (sel == 0) ? g0 : (sel == 1) ? g1 : g2;
    const float* bw = (sel == 0) ? b0 : (sel == 1) ? b1 : b2;
    ln_row(x, gw, bw, y + ((size_t)sel << 24), row);
}

// ---------------- fp32 -> bf16 cast of the 3 weight matrices ----------------
__global__ __launch_bounds__(256)
void cast3_kernel(const float* __restrict__ wa, const float* __restrict__ wb,
                  const float* __restrict__ wc, u16* __restrict__ oa) {
    const int bid = blockIdx.x;
    const int sel = bid >> 10;
    const float* s = (sel == 0) ? wa : (sel == 1) ? wb : wc;
    u16* d = oa + (size_t)sel * 1048576;
    const int i = (bid & 1023) * 256 + threadIdx.x;
    const float4 v = ((const float4*)s)[i];
    u16 o[4] = { f2bf(v.x), f2bf(v.y), f2bf(v.z), f2bf(v.w) };
    *(uint2*)(d + (size_t)i * 4) = *(uint2*)o;
}

// ---------------- old 128x128 GEMM (kept for MODE 3 / fallback) -----------
template<int MODE>
__global__ __launch_bounds__(256, (MODE == 3 ? 3 : 4))
void gemm_bt(const u16* __restrict__ A, const u16* __restrict__ B,
             const float* __restrict__ bias0, const float* __restrict__ bias1,
             const float* __restrict__ bias2,
             void* __restrict__ Cout, void* __restrict__ Cout2,
             const int M, const int N, const int K, const float scale,
             const long sA, const long sB, const long sC)
{
    int bz, m0, n0;
    if (MODE == 2 || MODE == 3) {
        const int id = blockIdx.x;
        bz = id & 7;                      // one batch per XCD
        m0 = ((id >> 3) & 15) * 128;
        n0 = (id >> 7) * 128;
    } else {
        bz = (MODE == 4) ? blockIdx.z : 0;
        m0 = blockIdx.x * 128;
        n0 = blockIdx.y * 128;
    }
    A += (long)bz * sA;
    B += (long)bz * sB;
    const float* bias = (MODE == 4) ? (bz == 0 ? bias0 : bz == 1 ? bias1 : bias2)
                                    : bias0;
    __shared__ __align__(16) u16 As[128 * 64];
    __shared__ __align__(16) u16 Bs[128 * 64];
    const int tid  = threadIdx.x;
    const int lane = tid & 63, wid = tid >> 6;
    const int wm = (wid & 1) * 64, wn = (wid >> 1) * 64;

    const int scol = (tid & 7) ^ ((tid >> 3) & 7);
    const u16* ap = A + (long)(m0 + (tid >> 3)) * K + scol * 8;
    const u16* bp = B + (long)(n0 + (tid >> 3)) * K + scol * 8;
    u16* asd = As + wid * 512;
    u16* bsd = Bs + wid * 512;
    const long rs32 = 32L * K;

    f32x4 acc[4][4] = {};
    f32x4 acc_l[4] = {};
    const short8 ones8 = {16256, 16256, 16256, 16256, 16256, 16256, 16256, 16256};
    const int fr = lane & 15, fq = lane >> 4;
    const int sw = (fq ^ (fr & 7)) * 8;
    const int offA0 = (wm + fr) * 64 + sw;
    const int offA1 = offA0 ^ 32;
    const int offB0 = (wn + fr) * 64 + sw;
    const int offB1 = offB0 ^ 32;

    for (int k0 = 0; k0 < K; k0 += 64) {
#pragma unroll
        for (int rd = 0; rd < 4; rd++) {
            load_lds16(ap + k0 + rd * rs32, asd + rd * 2048);
            load_lds16(bp + k0 + rd * rs32, bsd + rd * 2048);
        }
        __syncthreads();
#pragma unroll
        for (int s = 0; s < 2; s++) {
            const int oa = s ? offA1 : offA0;
            const int ob = s ? offB1 : offB0;
            short8 b0 = *(const short8*)&Bs[ob];
            short8 b1 = *(const short8*)&Bs[ob + 1024];
            short8 b2 = *(const short8*)&Bs[ob + 2048];
            short8 b3 = *(const short8*)&Bs[ob + 3072];
#pragma unroll
            for (int i = 0; i < 4; i++) {
                const short8 a = *(const short8*)&As[oa + i * 1024];
                acc[i][0] = __builtin_amdgcn_mfma_f32_16x16x32_bf16(a, b0, acc[i][0], 0, 0, 0);
                acc[i][1] = __builtin_amdgcn_mfma_f32_16x16x32_bf16(a, b1, acc[i][1], 0, 0, 0);
                acc[i][2] = __builtin_amdgcn_mfma_f32_16x16x32_bf16(a, b2, acc[i][2], 0, 0, 0);
                acc[i][3] = __builtin_amdgcn_mfma_f32_16x16x32_bf16(a, b3, acc[i][3], 0, 0, 0);
                if (MODE == 3)
                    acc_l[i] = __builtin_amdgcn_mfma_f32_16x16x32_bf16(a, ones8, acc_l[i], 0, 0, 0);
            }
        }
        __syncthreads();
    }

    const int cn = lane & 15;
    const int cm = (lane >> 4) * 4;
    float invl[4][4];
    if (MODE == 3) {
#pragma unroll
        for (int i = 0; i < 4; i++)
#pragma unroll
            for (int r = 0; r < 4; r++) invl[i][r] = 1.0f / acc_l[i][r];
    }
#pragma unroll
    for (int i = 0; i < 4; i++) {
        const int gmb = m0 + wm + i * 16 + cm;
#pragma unroll
        for (int j = 0; j < 4; j++) {
            const int gn = n0 + wn + j * 16 + cn;
            const float bv = (MODE <= 1 || MODE == 4) ? bias[gn] : 0.0f;
            if (MODE == 1 || (MODE == 4 && bz == 2)) {
                u16* dst = (MODE == 4) ? (u16*)Cout2 : (u16*)Cout;
                const int batch = gmb >> 11;
                const int jj = gmb & 2047;
                u16 o[4];
#pragma unroll
                for (int r = 0; r < 4; r++) o[r] = f2bf(acc[i][j][r] + bv);
                *(uint2*)(dst + ((long)batch * N + gn) * 2048 + jj) = *(uint2*)o;
            } else if (MODE == 0 || MODE == 4) {
                u16* dst = (u16*)Cout + ((MODE == 4) ? (long)bz * 16777216 : 0);
#pragma unroll
                for (int r = 0; r < 4; r++)
                    dst[(long)(gmb + r) * N + gn] = f2bf(acc[i][j][r] + bv);
            } else {
#pragma unroll
                for (int r = 0; r < 4; r++) {
                    const long gm = gmb + r;
                    float v = acc[i][j][r];
                    if (MODE == 2) v = __expf(v * scale);
                    if (MODE == 3)
                        ((float*)Cout)[(long)bz * sC + gm * N + gn] = v * invl[i][r];
                    else
                        ((u16*)Cout)[(long)bz * sC + gm * N + gn] = f2bf(v);
                }
            }
        }
    }
}

// ================= 256x256 8-phase quadrant GEMM (r10) ====================
// r9 post-mortem: lgkmcnt(0) BEFORE the pre-MFMA barrier forced every wave's
// LDS drain to gate ALL waves -> per-phase LDS drain and MFMA serialized
// (MfmaUtil 30%, tied with old 128^2 kernel). r10: m201 ordering —
//   {ds_reads; stage; s_barrier; s_waitcnt lgkmcnt(0); setprio1; MFMA;
//    setprio0; s_barrier}
// so waves stagger: first-drained wave MFMAs while others' reads drain.
// Correctness unchanged: each phase's reads drain (post-barrier lgkm0) before
// its MFMA, which precedes the phase-end barrier, which precedes any later
// overwriting stage. vmcnt gates only at P4/P8 (retire prev tile's 8 loads).
__device__ __forceinline__ void ph_mid() {      // after reads+stage issued
    __builtin_amdgcn_sched_barrier(0);
    __builtin_amdgcn_s_barrier();
    asm volatile("s_waitcnt lgkmcnt(0)" ::: "memory");
    __builtin_amdgcn_sched_barrier(0);
}
__device__ __forceinline__ void ph_end() {      // after MFMA cluster
    __builtin_amdgcn_sched_barrier(0);
    __builtin_amdgcn_s_barrier();
    __builtin_amdgcn_sched_barrier(0);
}

// A-half: 4 m-tiles x 2 k-slices (8 x ds_read_b128)
#define RDAH(reg, mh) do { \
    aF[0] = *(const short8*)&(reg)[ offA + ((mh)*4+0)*1024];        \
    aF[1] = *(const short8*)&(reg)[(offA + ((mh)*4+0)*1024) ^ 32];  \
    aF[2] = *(const short8*)&(reg)[ offA + ((mh)*4+1)*1024];        \
    aF[3] = *(const short8*)&(reg)[(offA + ((mh)*4+1)*1024) ^ 32];  \
    aF[4] = *(const short8*)&(reg)[ offA + ((mh)*4+2)*1024];        \
    aF[5] = *(const short8*)&(reg)[(offA + ((mh)*4+2)*1024) ^ 32];  \
    aF[6] = *(const short8*)&(reg)[ offA + ((mh)*4+3)*1024];        \
    aF[7] = *(const short8*)&(reg)[(offA + ((mh)*4+3)*1024) ^ 32];  } while (0)

// B-half: 2 n-tiles x 2 k-slices (4 x ds_read_b128)
#define RDBH(dst, reg, nh) do { \
    dst[0] = *(const short8*)&(reg)[ offB + ((nh)*2+0)*1024];        \
    dst[1] = *(const short8*)&(reg)[(offB + ((nh)*2+0)*1024) ^ 32];  \
    dst[2] = *(const short8*)&(reg)[ offB + ((nh)*2+1)*1024];        \
    dst[3] = *(const short8*)&(reg)[(offB + ((nh)*2+1)*1024) ^ 32];  } while (0)

// one C-quadrant x K=64: 16 MFMA; per-acc order s0 then s1
#define MMQ(mh, nh, bF) do { \
    __builtin_amdgcn_s_setprio(1); \
    _Pragma("unroll") \
    for (int i_ = 0; i_ < 4; i_++) { \
        _Pragma("unroll") \
        for (int j_ = 0; j_ < 2; j_++) { \
            acc[(mh)*4+i_][(nh)*2+j_] = __builtin_amdgcn_mfma_f32_16x16x32_bf16( \
                aF[2*i_],   bF[2*j_],   acc[(mh)*4+i_][(nh)*2+j_], 0, 0, 0); \
            acc[(mh)*4+i_][(nh)*2+j_] = __builtin_amdgcn_mfma_f32_16x16x32_bf16( \
                aF[2*i_+1], bF[2*j_+1], acc[(mh)*4+i_][(nh)*2+j_], 0, 0, 0); \
        } \
    } \
    __builtin_amdgcn_s_setprio(0); } while (0)

#define STA(reg, hm, kt) do { \
    const u16* s_ = apg + (hm) * rH + (long)(kt) * 64; \
    u16* d_ = (reg) + (hm) * 8192 + w * 1024; \
    load_lds16(s_, d_); \
    load_lds16(s_ + rK8, d_ + 512); } while (0)

#define STB(reg, hm, kt) do { \
    const u16* s_ = bpg + (hm) * rH + (long)(kt) * 64; \
    u16* d_ = (reg) + (hm) * 8192 + w * 1024; \
    load_lds16(s_, d_); \
    load_lds16(s_ + rK8, d_ + 512); } while (0)

// MODE 2: bf16 out = exp(acc*scale), per-batch grid decode (batch = XCD)
// MODE 4: merged QKV, grid(M/256, N/256, 3); z<2 row-major +bias, z=2 vT
template<int MODE>
__global__ __launch_bounds__(512, 1)
void gemm8(const u16* __restrict__ A, const u16* __restrict__ B,
           const float* __restrict__ bias0, const float* __restrict__ bias1,
           const float* __restrict__ bias2,
           void* __restrict__ Cout, void* __restrict__ Cout2,
           const int M, const int N, const int K, const float scale,
           const long sA, const long sB, const long sC)
{
    int bz, m0, n0;
    if (MODE == 2) {
        const int id = blockIdx.x;
        bz = id & 7;                      // one batch per XCD
        m0 = ((id >> 3) & 7) * 256;
        n0 = (id >> 6) * 256;
    } else {
        bz = blockIdx.z;
        m0 = blockIdx.x * 256;
        n0 = blockIdx.y * 256;
    }
    A += (long)bz * sA;
    B += (long)bz * sB;
    const float* bias = (MODE == 4) ? (bz == 0 ? bias0 : bz == 1 ? bias1 : bias2)
                                    : bias0;

    __shared__ __align__(16) u16 lds[65536];   // 128 KiB
    u16* const Ar0 = lds;
    u16* const Ar1 = lds + 16384;
    u16* const Br0 = lds + 32768;
    u16* const Br1 = lds + 49152;

    const int tid = threadIdx.x;
    const int w = tid >> 6, l = tid & 63;
    // staging: wave w covers rows w*16 + (l>>3) (+8 for 2nd load) of a
    // 128-row half; global col-group pre-swizzled so the linear LDS fill
    // realizes LDS[r*64 + ((cg ^ (r&7))*8)] = global cols cg*8.. of row r.
    const int cgrp = (l & 7) ^ ((l >> 3) & 7);
    const long rK8 = 8L * K;
    const long rH  = 128L * K;
    const u16* apg = A + (long)(m0 + w * 16 + (l >> 3)) * K + cgrp * 8;
    const u16* bpg = B + (long)(n0 + w * 16 + (l >> 3)) * K + cgrp * 8;

    const int wm = (w & 1) * 128;         // 2 waves along M (per-wave 128 rows)
    const int wn = (w >> 1) * 64;         // 4 waves along N (per-wave 64 cols)
    const int fr = l & 15, fq = l >> 4;
    const int sw8 = (fq ^ (fr & 7)) * 8;
    const int offA = (wm + fr) * 64 + sw8;   // +i*1024 per m-tile, ^32 for s=1
    const int offB = (wn + fr) * 64 + sw8;   // +j*1024 per n-tile

    f32x4 acc[8][4] = {};
    short8 aF[8];
    short8 bF0[4], bF1[4];

    // prologue: tile0 -> buf0, tile1 -> buf1 (B-halves then A-halves each)
    STB(Br0, 0, 0); STB(Br0, 1, 0); STA(Ar0, 0, 0); STA(Ar0, 1, 0);
    STB(Br1, 0, 1); STB(Br1, 1, 1); STA(Ar1, 0, 1); STA(Ar1, 1, 1);
    __builtin_amdgcn_sched_barrier(0);
    asm volatile("s_waitcnt vmcnt(8)" ::: "memory");   // tile0 landed
    __builtin_amdgcn_s_barrier();
    asm volatile("" ::: "memory");
    __builtin_amdgcn_sched_barrier(0);

    const int NI = K >> 7;                // 2 K-tiles per iteration
    for (int it = 0; it < NI; ++it) {
        const bool nl = (it < NI - 1);
        const int t2 = 2 * it + 2, t3 = 2 * it + 3;
        // ---- tile 2it from buf0 ----
        // P1: rd A-h0 (8) + B-h0 (4); MFMA Q00
        RDAH(Ar0, 0); RDBH(bF0, Br0, 0);
        ph_mid();
        MMQ(0, 0, bF0);
        ph_end();
        // P2: rd B-h1 (4); MFMA Q01
        RDBH(bF1, Br0, 1);
        ph_mid();
        MMQ(0, 1, bF1);
        ph_end();
        // P3: rd A-h1 (8); stage B(t2) both halves; MFMA Q10
        RDAH(Ar0, 1);
        if (nl) { STB(Br0, 0, t2); STB(Br0, 1, t2); }
        ph_mid();
        MMQ(1, 0, bF0);
        ph_end();
        // P4: stage A(t2) both halves; MFMA Q11; gate vmcnt -> buf1 landed
        if (nl) { STA(Ar0, 0, t2); STA(Ar0, 1, t2); }
        ph_mid();
        MMQ(1, 1, bF1);
        __builtin_amdgcn_sched_barrier(0);
        if (nl) asm volatile("s_waitcnt vmcnt(8)" ::: "memory");
        else    asm volatile("s_waitcnt vmcnt(0)" ::: "memory");
        __builtin_amdgcn_s_barrier();
        asm volatile("" ::: "memory");
        __builtin_amdgcn_sched_barrier(0);
        // ---- tile 2it+1 from buf1 ----
        // P5: rd A-h0 + B-h0; MFMA Q00
        RDAH(Ar1, 0); RDBH(bF0, Br1, 0);
        ph_mid();
        MMQ(0, 0, bF0);
        ph_end();
        // P6: rd B-h1; MFMA Q01
        RDBH(bF1, Br1, 1);
        ph_mid();
        MMQ(0, 1, bF1);
        ph_end();
        // P7: rd A-h1; stage B(t3); MFMA Q10
        RDAH(Ar1, 1);
        if (nl) { STB(Br1, 0, t3); STB(Br1, 1, t3); }
        ph_mid();
        MMQ(1, 0, bF0);
        ph_end();
        // P8: stage A(t3); MFMA Q11; gate vmcnt -> buf0 (t2) landed
        if (nl) { STA(Ar1, 0, t3); STA(Ar1, 1, t3); }
        ph_mid();
        MMQ(1, 1, bF1);
        __builtin_amdgcn_sched_barrier(0);
        if (nl) asm volatile("s_waitcnt vmcnt(8)" ::: "memory");
        else    asm volatile("s_waitcnt vmcnt(0)" ::: "memory");
        __builtin_amdgcn_s_barrier();
        asm volatile("" ::: "memory");
        __builtin_amdgcn_sched_barrier(0);
    }

    // epilogue: C/D layout col=lane&15, row=(lane>>4)*4+r
    const int cn = l & 15, cm = (l >> 4) * 4;
#pragma unroll
    for (int i = 0; i < 8; i++) {
        const int gmb = m0 + wm + i * 16 + cm;
#pragma unroll
        for (int j = 0; j < 4; j++) {
            const int gn = n0 + wn + j * 16 + cn;
            if (MODE == 4) {
                const float bv = bias[gn];
                if (bz == 2) {
                    const int batch = gmb >> 11, jj = gmb & 2047;
                    u16 o[4];
#pragma unroll
                    for (int r = 0; r < 4; r++) o[r] = f2bf(acc[i][j][r] + bv);
                    *(uint2*)((u16*)Cout2 + ((long)batch * N + gn) * 2048 + jj) = *(uint2*)o;
                } else {
                    u16* dst = (u16*)Cout + (long)bz * ((long)M * N);
#pragma unroll
                    for (int r = 0; r < 4; r++)
                        dst[(long)(gmb + r) * N + gn] = f2bf(acc[i][j][r] + bv);
                }
            } else {
#pragma unroll
                for (int r = 0; r < 4; r++)
                    ((u16*)Cout)[(long)bz * sC + (long)(gmb + r) * N + gn] =
                        f2bf(__expf(acc[i][j][r] * scale));
            }
        }
    }
}

extern "C" void kernel_launch(void* const* d_in, const int* in_sizes, int n_in,
                              void* d_out, int out_size, void* d_ws, size_t ws_size,
                              hipStream_t stream) {
    const float* target = (const float*)d_in[0];
    const float* src_k  = (const float*)d_in[1];
    const float* src_v  = (const float*)d_in[2];
    const float* Wq = (const float*)d_in[3];
    const float* bq = (const float*)d_in[4];
    const float* Wk = (const float*)d_in[5];
    const float* bk = (const float*)d_in[6];
    const float* Wv = (const float*)d_in[7];
    const float* bv = (const float*)d_in[8];
    const float* g_t = (const float*)d_in[9];
    const float* b_t = (const float*)d_in[10];
    const float* g_k = (const float*)d_in[11];
    const float* b_k = (const float*)d_in[12];
    const float* g_v = (const float*)d_in[13];
    const float* b_v = (const float*)d_in[14];

    char* ws = (char*)d_ws;
    const float scale = 0.03125f;  // 1024^-0.5
    const size_t MB = 1048576;

    if (ws_size >= 198 * MB) {
        // merged path: peak 198 MB
        u16* q   = (u16*)(ws + 0);            // 16384x1024 bf16 (q,kk contiguous)
        u16* kk  = (u16*)(ws + 32 * MB);
        u16* vT  = (u16*)(ws + 64 * MB);      // 8 x 1024 x 2048 bf16
        u16* ln3 = (u16*)(ws + 96 * MB);      // 3 x 16384x1024 bf16 (dead after proj)
        u16* wqb = (u16*)(ws + 192 * MB);     // 3 x 1024x1024 bf16
        u16* S   = (u16*)(ws + 96 * MB);      // 8x2048x2048 bf16 (aliases ln3)

        cast3_kernel<<<3072, 256, 0, stream>>>(Wq, Wk, Wv, wqb);
        ln3_kernel<<<49152, 256, 0, stream>>>(target, src_k, src_v,
                                              g_t, g_k, g_v, b_t, b_k, b_v, ln3);
        // Q/K/V projections: 256^2 8-phase kernel, one dispatch (z = projection)
        gemm8<4><<<dim3(64, 4, 3), 512, 0, stream>>>(ln3, wqb, bq, bk, bv,
            q, vT, 16384, 1024, 1024, 1.0f, 16777216L, 1048576L, 0);
        // P[b] = exp((q[b] @ k[b]^T) * scale): 256^2 8-phase
        gemm8<2><<<512, 512, 0, stream>>>(q, kk, nullptr, nullptr, nullptr, S, nullptr,
            2048, 2048, 1024, scale, 2048L * 1024, 2048L * 1024, 2048L * 2048);
        // out[b] = (P[b] @ vT[b]^T) / rowsum(P[b])  (old kernel; port later)
        gemm_bt<3><<<1024, 256, 0, stream>>>(S, vT, nullptr, nullptr, nullptr, d_out, nullptr,
            2048, 1024, 2048, 1.0f, 2048L * 2048, 1024L * 2048, 2048L * 1024);
    } else {
        // fallback (r6) path: peak ~140.5 MB
        u16* q   = (u16*)(ws + 0);
        u16* kk  = (u16*)(ws + 32 * MB);
        u16* vT  = (u16*)(ws + 64 * MB);
        u16* ln  = (u16*)(ws + 96 * MB);
        u16* wqb = (u16*)(ws + 128 * MB);
        u16* wkb = wqb + 1048576;
        u16* wvb = wkb + 1048576;
        u16* S   = (u16*)(ws + 96 * MB);

        cast3_kernel<<<3072, 256, 0, stream>>>(Wq, Wk, Wv, wqb);
        ln_cast_kernel<<<16384, 256, 0, stream>>>(target, g_t, b_t, ln);
        gemm_bt<0><<<dim3(128, 8, 1), 256, 0, stream>>>(ln, wqb, bq, nullptr, nullptr,
            q, nullptr, 16384, 1024, 1024, 1.0f, 0, 0, 0);
        ln_cast_kernel<<<16384, 256, 0, stream>>>(src_k, g_k, b_k, ln);
        gemm_bt<0><<<dim3(128, 8, 1), 256, 0, stream>>>(ln, wkb, bk, nullptr, nullptr,
            kk, nullptr, 16384, 1024, 1024, 1.0f, 0, 0, 0);
        ln_cast_kernel<<<16384, 256, 0, stream>>>(src_v, g_v, b_v, ln);
        gemm_bt<1><<<dim3(128, 8, 1), 256, 0, stream>>>(ln, wvb, bv, nullptr, nullptr,
            vT, nullptr, 16384, 1024, 1024, 1.0f, 0, 0, 0);
        gemm_bt<2><<<2048, 256, 0, stream>>>(q, kk, nullptr, nullptr, nullptr, S, nullptr,
            2048, 2048, 1024, scale, 2048L * 1024, 2048L * 1024, 2048L * 2048);
        gemm_bt<3><<<1024, 256, 0, stream>>>(S, vT, nullptr, nullptr, nullptr, d_out, nullptr,
            2048, 1024, 2048, 1.0f, 2048L * 2048, 1024L * 2048, 2048L * 1024);
    }
}

// Round 5
// 496.101 us; speedup vs baseline: 2.3221x; 1.0177x over previous
//
#include <hip/hip_runtime.h>
#include <cstdint>

using u16 = unsigned short;
using u32 = unsigned int;
typedef __attribute__((ext_vector_type(8))) short short8;
typedef __attribute__((ext_vector_type(4))) float f32x4;

__device__ __forceinline__ float bf2f(u16 u) { return __uint_as_float(((u32)u) << 16); }
__device__ __forceinline__ u16 f2bf(float f) {
    u32 u = __float_as_uint(f);
    u32 r = u + 0x7fffu + ((u >> 16) & 1u);   // round-to-nearest-even
    return (u16)(r >> 16);
}

__device__ __forceinline__ void load_lds16(const void* g, void* l) {
    __builtin_amdgcn_global_load_lds((const __attribute__((address_space(1))) void*)g,
                                     (__attribute__((address_space(3))) void*)l, 16, 0, 0);
}

// ---------------- LayerNorm row body (1024 fp32 -> bf16) ----------------
__device__ __forceinline__ void ln_row(const float* __restrict__ x,
                                       const float* __restrict__ gw,
                                       const float* __restrict__ bw,
                                       u16* __restrict__ y, int row) {
    const int tid = threadIdx.x;
    const float4 v = ((const float4*)(x + (size_t)row * 1024))[tid];
    float s  = v.x + v.y + v.z + v.w;
    float ss = v.x * v.x + v.y * v.y + v.z * v.z + v.w * v.w;
#pragma unroll
    for (int off = 32; off; off >>= 1) {
        s  += __shfl_xor(s, off);
        ss += __shfl_xor(ss, off);
    }
    __shared__ float sm[8];
    const int lane = tid & 63, wid = tid >> 6;
    if (lane == 0) { sm[wid] = s; sm[wid + 4] = ss; }
    __syncthreads();
    s  = sm[0] + sm[1] + sm[2] + sm[3];
    ss = sm[4] + sm[5] + sm[6] + sm[7];
    const float mu   = s * (1.0f / 1024.0f);
    const float var  = ss * (1.0f / 1024.0f) - mu * mu;
    const float rstd = rsqrtf(var + 1e-5f);
    const float4 g4 = ((const float4*)gw)[tid];
    const float4 b4 = ((const float4*)bw)[tid];
    u16 o[4];
    o[0] = f2bf((v.x - mu) * rstd * g4.x + b4.x);
    o[1] = f2bf((v.y - mu) * rstd * g4.y + b4.y);
    o[2] = f2bf((v.z - mu) * rstd * g4.z + b4.z);
    o[3] = f2bf((v.w - mu) * rstd * g4.w + b4.w);
    *(uint2*)(y + (size_t)row * 1024 + tid * 4) = *(uint2*)o;
}

__global__ __launch_bounds__(256)
void ln_cast_kernel(const float* __restrict__ x, const float* __restrict__ gw,
                    const float* __restrict__ bw, u16* __restrict__ y) {
    ln_row(x, gw, bw, y, blockIdx.x);
}

// merged: all 3 layernorms in one dispatch (sel = bid>>14)
__global__ __launch_bounds__(256)
void ln3_kernel(const float* __restrict__ x0, const float* __restrict__ x1,
                const float* __restrict__ x2,
                const float* __restrict__ g0, const float* __restrict__ g1,
                const float* __restrict__ g2,
                const float* __restrict__ b0, const float* __restrict__ b1,
                const float* __restrict__ b2, u16* __restrict__ y) {
    const int bid = blockIdx.x;
    const int sel = bid >> 14;
    const int row = bid & 16383;
    const float* x  = (sel == 0) ? x0 : (sel == 1) ? x1 : x2;
    const float* gw = (sel == 0) ? g0 : (sel == 1) ? g1 : g2;
    const float* bw = (sel == 0) ? b0 : (sel == 1) ? b1 : b2;
    ln_row(x, gw, bw, y + ((size_t)sel << 24), row);
}

// ---------------- fp32 -> bf16 cast of the 3 weight matrices ----------------
__global__ __launch_bounds__(256)
void cast3_kernel(const float* __restrict__ wa, const float* __restrict__ wb,
                  const float* __restrict__ wc, u16* __restrict__ oa) {
    const int bid = blockIdx.x;
    const int sel = bid >> 10;
    const float* s = (sel == 0) ? wa : (sel == 1) ? wb : wc;
    u16* d = oa + (size_t)sel * 1048576;
    const int i = (bid & 1023) * 256 + threadIdx.x;
    const float4 v = ((const float4*)s)[i];
    u16 o[4] = { f2bf(v.x), f2bf(v.y), f2bf(v.z), f2bf(v.w) };
    *(uint2*)(d + (size_t)i * 4) = *(uint2*)o;
}

// ---------------- old 128x128 GEMM (kept for MODE 3 / fallback) -----------
template<int MODE>
__global__ __launch_bounds__(256, (MODE == 3 ? 3 : 4))
void gemm_bt(const u16* __restrict__ A, const u16* __restrict__ B,
             const float* __restrict__ bias0, const float* __restrict__ bias1,
             const float* __restrict__ bias2,
             void* __restrict__ Cout, void* __restrict__ Cout2,
             const int M, const int N, const int K, const float scale,
             const long sA, const long sB, const long sC)
{
    int bz, m0, n0;
    if (MODE == 2 || MODE == 3) {
        const int id = blockIdx.x;
        bz = id & 7;                      // one batch per XCD
        m0 = ((id >> 3) & 15) * 128;
        n0 = (id >> 7) * 128;
    } else {
        bz = (MODE == 4) ? blockIdx.z : 0;
        m0 = blockIdx.x * 128;
        n0 = blockIdx.y * 128;
    }
    A += (long)bz * sA;
    B += (long)bz * sB;
    const float* bias = (MODE == 4) ? (bz == 0 ? bias0 : bz == 1 ? bias1 : bias2)
                                    : bias0;
    __shared__ __align__(16) u16 As[128 * 64];
    __shared__ __align__(16) u16 Bs[128 * 64];
    const int tid  = threadIdx.x;
    const int lane = tid & 63, wid = tid >> 6;
    const int wm = (wid & 1) * 64, wn = (wid >> 1) * 64;

    const int scol = (tid & 7) ^ ((tid >> 3) & 7);
    const u16* ap = A + (long)(m0 + (tid >> 3)) * K + scol * 8;
    const u16* bp = B + (long)(n0 + (tid >> 3)) * K + scol * 8;
    u16* asd = As + wid * 512;
    u16* bsd = Bs + wid * 512;
    const long rs32 = 32L * K;

    f32x4 acc[4][4] = {};
    f32x4 acc_l[4] = {};
    const short8 ones8 = {16256, 16256, 16256, 16256, 16256, 16256, 16256, 16256};
    const int fr = lane & 15, fq = lane >> 4;
    const int sw = (fq ^ (fr & 7)) * 8;
    const int offA0 = (wm + fr) * 64 + sw;
    const int offA1 = offA0 ^ 32;
    const int offB0 = (wn + fr) * 64 + sw;
    const int offB1 = offB0 ^ 32;

    for (int k0 = 0; k0 < K; k0 += 64) {
#pragma unroll
        for (int rd = 0; rd < 4; rd++) {
            load_lds16(ap + k0 + rd * rs32, asd + rd * 2048);
            load_lds16(bp + k0 + rd * rs32, bsd + rd * 2048);
        }
        __syncthreads();
#pragma unroll
        for (int s = 0; s < 2; s++) {
            const int oa = s ? offA1 : offA0;
            const int ob = s ? offB1 : offB0;
            short8 b0 = *(const short8*)&Bs[ob];
            short8 b1 = *(const short8*)&Bs[ob + 1024];
            short8 b2 = *(const short8*)&Bs[ob + 2048];
            short8 b3 = *(const short8*)&Bs[ob + 3072];
#pragma unroll
            for (int i = 0; i < 4; i++) {
                const short8 a = *(const short8*)&As[oa + i * 1024];
                acc[i][0] = __builtin_amdgcn_mfma_f32_16x16x32_bf16(a, b0, acc[i][0], 0, 0, 0);
                acc[i][1] = __builtin_amdgcn_mfma_f32_16x16x32_bf16(a, b1, acc[i][1], 0, 0, 0);
                acc[i][2] = __builtin_amdgcn_mfma_f32_16x16x32_bf16(a, b2, acc[i][2], 0, 0, 0);
                acc[i][3] = __builtin_amdgcn_mfma_f32_16x16x32_bf16(a, b3, acc[i][3], 0, 0, 0);
                if (MODE == 3)
                    acc_l[i] = __builtin_amdgcn_mfma_f32_16x16x32_bf16(a, ones8, acc_l[i], 0, 0, 0);
            }
        }
        __syncthreads();
    }

    const int cn = lane & 15;
    const int cm = (lane >> 4) * 4;
    float invl[4][4];
    if (MODE == 3) {
#pragma unroll
        for (int i = 0; i < 4; i++)
#pragma unroll
            for (int r = 0; r < 4; r++) invl[i][r] = 1.0f / acc_l[i][r];
    }
#pragma unroll
    for (int i = 0; i < 4; i++) {
        const int gmb = m0 + wm + i * 16 + cm;
#pragma unroll
        for (int j = 0; j < 4; j++) {
            const int gn = n0 + wn + j * 16 + cn;
            const float bv = (MODE <= 1 || MODE == 4) ? bias[gn] : 0.0f;
            if (MODE == 1 || (MODE == 4 && bz == 2)) {
                u16* dst = (MODE == 4) ? (u16*)Cout2 : (u16*)Cout;
                const int batch = gmb >> 11;
                const int jj = gmb & 2047;
                u16 o[4];
#pragma unroll
                for (int r = 0; r < 4; r++) o[r] = f2bf(acc[i][j][r] + bv);
                *(uint2*)(dst + ((long)batch * N + gn) * 2048 + jj) = *(uint2*)o;
            } else if (MODE == 0 || MODE == 4) {
                u16* dst = (u16*)Cout + ((MODE == 4) ? (long)bz * 16777216 : 0);
#pragma unroll
                for (int r = 0; r < 4; r++)
                    dst[(long)(gmb + r) * N + gn] = f2bf(acc[i][j][r] + bv);
            } else {
#pragma unroll
                for (int r = 0; r < 4; r++) {
                    const long gm = gmb + r;
                    float v = acc[i][j][r];
                    if (MODE == 2) v = __expf(v * scale);
                    if (MODE == 3)
                        ((float*)Cout)[(long)bz * sC + gm * N + gn] = v * invl[i][r];
                    else
                        ((u16*)Cout)[(long)bz * sC + gm * N + gn] = f2bf(v);
                }
            }
        }
    }
}

// ================= 256x256 8-phase quadrant GEMM (r11) ====================
// r10 post-mortem: barrier order was not the stall. Found mechanism: MMQ
// issued dependent MFMA pairs back-to-back (s0->s1 on the SAME acc, dep
// distance 1; MFMA result latency ~3-4x issue cost; 2 waves/SIMD can't hide).
// r11 fix 1: k-slice OUTERMOST in the 16-MFMA cluster -> dep distance 8.
// r11 fix 2: half-local quadrant remap — per-wave rows = mh*128+(w&1)*64+..,
// cols = nh*128+(w>>1)*32+.. so each read quadrant touches exactly ONE
// staging half; staging then spreads (P2: Bh0+Ah0, P3: Bh1, P4: Ah1) for the
// fine ds_read||stage||MFMA interleave (m196). Safety: a half is staged only
// in a phase strictly after its last ds_read phase (reads complete at that
// phase's mid-lgkm, stage issues after the phase-end barrier). vmcnt per wave:
// enter 8 -> P2 12 -> P3 14 -> P4 16, gate vmcnt(8) retires exactly the tile
// needed for the next 4 phases. Per-acc K order unchanged (tiles ascending,
// s0 then s1) -> numerics identical to r8/r9/r10 (all passed).
__device__ __forceinline__ void ph_mid() {      // after reads+stage issued
    __builtin_amdgcn_sched_barrier(0);
    __builtin_amdgcn_s_barrier();
    asm volatile("s_waitcnt lgkmcnt(0)" ::: "memory");
    __builtin_amdgcn_sched_barrier(0);
}
__device__ __forceinline__ void ph_end() {      // after MFMA cluster
    __builtin_amdgcn_sched_barrier(0);
    __builtin_amdgcn_s_barrier();
    __builtin_amdgcn_sched_barrier(0);
}

// A-half quadrant mh: 4 m-tiles x 2 k-slices (8 x ds_read_b128), rows
// mh*128 + (w&1)*64 + i*16 + fr  ->  elems offA + mh*8192 + i*1024 (^32 k1)
#define RDAH(reg, mh) do { \
    aF[0] = *(const short8*)&(reg)[ offA + (mh)*8192 + 0*1024];        \
    aF[1] = *(const short8*)&(reg)[(offA + (mh)*8192 + 0*1024) ^ 32];  \
    aF[2] = *(const short8*)&(reg)[ offA + (mh)*8192 + 1*1024];        \
    aF[3] = *(const short8*)&(reg)[(offA + (mh)*8192 + 1*1024) ^ 32];  \
    aF[4] = *(const short8*)&(reg)[ offA + (mh)*8192 + 2*1024];        \
    aF[5] = *(const short8*)&(reg)[(offA + (mh)*8192 + 2*1024) ^ 32];  \
    aF[6] = *(const short8*)&(reg)[ offA + (mh)*8192 + 3*1024];        \
    aF[7] = *(const short8*)&(reg)[(offA + (mh)*8192 + 3*1024) ^ 32];  } while (0)

// B-half quadrant nh: 2 n-tiles x 2 k-slices (4 x ds_read_b128), cols
// nh*128 + (w>>1)*32 + j*16 + fr  ->  elems offB + nh*8192 + j*1024 (^32 k1)
#define RDBH(dst, reg, nh) do { \
    dst[0] = *(const short8*)&(reg)[ offB + (nh)*8192 + 0*1024];        \
    dst[1] = *(const short8*)&(reg)[(offB + (nh)*8192 + 0*1024) ^ 32];  \
    dst[2] = *(const short8*)&(reg)[ offB + (nh)*8192 + 1*1024];        \
    dst[3] = *(const short8*)&(reg)[(offB + (nh)*8192 + 1*1024) ^ 32];  } while (0)

// one C-quadrant x K=64: 16 MFMA, k-slice OUTER (dep distance 8)
#define MMQ(mh, nh, bF) do { \
    __builtin_amdgcn_s_setprio(1); \
    _Pragma("unroll") \
    for (int s_ = 0; s_ < 2; s_++) { \
        _Pragma("unroll") \
        for (int i_ = 0; i_ < 4; i_++) { \
            _Pragma("unroll") \
            for (int j_ = 0; j_ < 2; j_++) \
                acc[(mh)*4+i_][(nh)*2+j_] = __builtin_amdgcn_mfma_f32_16x16x32_bf16( \
                    aF[2*i_+s_], bF[2*j_+s_], acc[(mh)*4+i_][(nh)*2+j_], 0, 0, 0); \
        } \
    } \
    __builtin_amdgcn_s_setprio(0); } while (0)

#define STA(reg, hm, kt) do { \
    const u16* s_ = apg + (hm) * rH + (long)(kt) * 64; \
    u16* d_ = (reg) + (hm) * 8192 + w * 1024; \
    load_lds16(s_, d_); \
    load_lds16(s_ + rK8, d_ + 512); } while (0)

#define STB(reg, hm, kt) do { \
    const u16* s_ = bpg + (hm) * rH + (long)(kt) * 64; \
    u16* d_ = (reg) + (hm) * 8192 + w * 1024; \
    load_lds16(s_, d_); \
    load_lds16(s_ + rK8, d_ + 512); } while (0)

// MODE 2: bf16 out = exp(acc*scale), per-batch grid decode (batch = XCD)
// MODE 4: merged QKV, grid(M/256, N/256, 3); z<2 row-major +bias, z=2 vT
template<int MODE>
__global__ __launch_bounds__(512, 1)
void gemm8(const u16* __restrict__ A, const u16* __restrict__ B,
           const float* __restrict__ bias0, const float* __restrict__ bias1,
           const float* __restrict__ bias2,
           void* __restrict__ Cout, void* __restrict__ Cout2,
           const int M, const int N, const int K, const float scale,
           const long sA, const long sB, const long sC)
{
    int bz, m0, n0;
    if (MODE == 2) {
        const int id = blockIdx.x;
        bz = id & 7;                      // one batch per XCD
        m0 = ((id >> 3) & 7) * 256;
        n0 = (id >> 6) * 256;
    } else {
        bz = blockIdx.z;
        m0 = blockIdx.x * 256;
        n0 = blockIdx.y * 256;
    }
    A += (long)bz * sA;
    B += (long)bz * sB;
    const float* bias = (MODE == 4) ? (bz == 0 ? bias0 : bz == 1 ? bias1 : bias2)
                                    : bias0;

    __shared__ __align__(16) u16 lds[65536];   // 128 KiB
    u16* const Ar0 = lds;
    u16* const Ar1 = lds + 16384;
    u16* const Br0 = lds + 32768;
    u16* const Br1 = lds + 49152;

    const int tid = threadIdx.x;
    const int w = tid >> 6, l = tid & 63;
    // staging: wave w covers rows w*16 + (l>>3) (+8 for 2nd load) of a
    // 128-row half; global col-group pre-swizzled so the linear LDS fill
    // realizes LDS[r*64 + ((cg ^ (r&7))*8)] = global cols cg*8.. of row r.
    const int cgrp = (l & 7) ^ ((l >> 3) & 7);
    const long rK8 = 8L * K;
    const long rH  = 128L * K;
    const u16* apg = A + (long)(m0 + w * 16 + (l >> 3)) * K + cgrp * 8;
    const u16* bpg = B + (long)(n0 + w * 16 + (l >> 3)) * K + cgrp * 8;

    const int w1 = w & 1;                 // M sub-band within a 128-row half
    const int wn2 = (w >> 1) * 32;        // N sub-band within a 128-col half
    const int fr = l & 15, fq = l >> 4;
    const int sw8 = (fq ^ (fr & 7)) * 8;
    const int offA = (w1 * 64 + fr) * 64 + sw8;   // + mh*8192 + i*1024
    const int offB = (wn2 + fr) * 64 + sw8;       // + nh*8192 + j*1024

    f32x4 acc[8][4] = {};
    short8 aF[8];
    short8 bF0[4], bF1[4];

    // prologue: tile0 -> buf0, tile1 -> buf1 (B-halves then A-halves each)
    STB(Br0, 0, 0); STB(Br0, 1, 0); STA(Ar0, 0, 0); STA(Ar0, 1, 0);
    STB(Br1, 0, 1); STB(Br1, 1, 1); STA(Ar1, 0, 1); STA(Ar1, 1, 1);
    __builtin_amdgcn_sched_barrier(0);
    asm volatile("s_waitcnt vmcnt(8)" ::: "memory");   // tile0 landed
    __builtin_amdgcn_s_barrier();
    asm volatile("" ::: "memory");
    __builtin_amdgcn_sched_barrier(0);

    const int NI = K >> 7;                // 2 K-tiles per iteration
    for (int it = 0; it < NI; ++it) {
        const bool nl = (it < NI - 1);
        const int t2 = 2 * it + 2, t3 = 2 * it + 3;
        // ---- tile 2it from buf0 ----
        // P1: rd A-q0 (8) + B-q0 (4); MFMA Q00   (touches halves Ah0, Bh0)
        RDAH(Ar0, 0); RDBH(bF0, Br0, 0);
        ph_mid();
        MMQ(0, 0, bF0);
        ph_end();
        // P2: rd B-q1 (4, half Bh1); stage Bh0(t2)+Ah0(t2); MFMA Q01
        RDBH(bF1, Br0, 1);
        if (nl) { STB(Br0, 0, t2); STA(Ar0, 0, t2); }
        ph_mid();
        MMQ(0, 1, bF1);
        ph_end();
        // P3: rd A-q1 (8, half Ah1); stage Bh1(t2); MFMA Q10
        RDAH(Ar0, 1);
        if (nl) STB(Br0, 1, t2);
        ph_mid();
        MMQ(1, 0, bF0);
        ph_end();
        // P4: stage Ah1(t2); MFMA Q11; gate vmcnt -> buf1 (odd tile) landed
        if (nl) STA(Ar0, 1, t2);
        ph_mid();
        MMQ(1, 1, bF1);
        __builtin_amdgcn_sched_barrier(0);
        if (nl) asm volatile("s_waitcnt vmcnt(8)" ::: "memory");
        else    asm volatile("s_waitcnt vmcnt(0)" ::: "memory");
        __builtin_amdgcn_s_barrier();
        asm volatile("" ::: "memory");
        __builtin_amdgcn_sched_barrier(0);
        // ---- tile 2it+1 from buf1 ----
        // P5: rd A-q0 + B-q0; MFMA Q00
        RDAH(Ar1, 0); RDBH(bF0, Br1, 0);
        ph_mid();
        MMQ(0, 0, bF0);
        ph_end();
        // P6: rd B-q1; stage Bh0(t3)+Ah0(t3); MFMA Q01
        RDBH(bF1, Br1, 1);
        if (nl) { STB(Br1, 0, t3); STA(Ar1, 0, t3); }
        ph_mid();
        MMQ(0, 1, bF1);
        ph_end();
        // P7: rd A-q1; stage Bh1(t3); MFMA Q10
        RDAH(Ar1, 1);
        if (nl) STB(Br1, 1, t3);
        ph_mid();
        MMQ(1, 0, bF0);
        ph_end();
        // P8: stage Ah1(t3); MFMA Q11; gate vmcnt -> buf0 (t2) landed
        if (nl) STA(Ar1, 1, t3);
        ph_mid();
        MMQ(1, 1, bF1);
        __builtin_amdgcn_sched_barrier(0);
        if (nl) asm volatile("s_waitcnt vmcnt(8)" ::: "memory");
        else    asm volatile("s_waitcnt vmcnt(0)" ::: "memory");
        __builtin_amdgcn_s_barrier();
        asm volatile("" ::: "memory");
        __builtin_amdgcn_sched_barrier(0);
    }

    // epilogue: C/D layout col=lane&15, row=(lane>>4)*4+r
    // acc[i][j]: global row = m0 + (i>>2)*128 + w1*64 + (i&3)*16 + cm
    //            global col = n0 + (j>>1)*128 + wn2 + (j&1)*16 + cn
    const int cn = l & 15, cm = (l >> 4) * 4;
#pragma unroll
    for (int i = 0; i < 8; i++) {
        const int gmb = m0 + (i >> 2) * 128 + w1 * 64 + (i & 3) * 16 + cm;
#pragma unroll
        for (int j = 0; j < 4; j++) {
            const int gn = n0 + (j >> 1) * 128 + wn2 + (j & 1) * 16 + cn;
            if (MODE == 4) {
                const float bv = bias[gn];
                if (bz == 2) {
                    const int batch = gmb >> 11, jj = gmb & 2047;
                    u16 o[4];
#pragma unroll
                    for (int r = 0; r < 4; r++) o[r] = f2bf(acc[i][j][r] + bv);
                    *(uint2*)((u16*)Cout2 + ((long)batch * N + gn) * 2048 + jj) = *(uint2*)o;
                } else {
                    u16* dst = (u16*)Cout + (long)bz * ((long)M * N);
#pragma unroll
                    for (int r = 0; r < 4; r++)
                        dst[(long)(gmb + r) * N + gn] = f2bf(acc[i][j][r] + bv);
                }
            } else {
#pragma unroll
                for (int r = 0; r < 4; r++)
                    ((u16*)Cout)[(long)bz * sC + (long)(gmb + r) * N + gn] =
                        f2bf(__expf(acc[i][j][r] * scale));
            }
        }
    }
}

extern "C" void kernel_launch(void* const* d_in, const int* in_sizes, int n_in,
                              void* d_out, int out_size, void* d_ws, size_t ws_size,
                              hipStream_t stream) {
    const float* target = (const float*)d_in[0];
    const float* src_k  = (const float*)d_in[1];
    const float* src_v  = (const float*)d_in[2];
    const float* Wq = (const float*)d_in[3];
    const float* bq = (const float*)d_in[4];
    const float* Wk = (const float*)d_in[5];
    const float* bk = (const float*)d_in[6];
    const float* Wv = (const float*)d_in[7];
    const float* bv = (const float*)d_in[8];
    const float* g_t = (const float*)d_in[9];
    const float* b_t = (const float*)d_in[10];
    const float* g_k = (const float*)d_in[11];
    const float* b_k = (const float*)d_in[12];
    const float* g_v = (const float*)d_in[13];
    const float* b_v = (const float*)d_in[14];

    char* ws = (char*)d_ws;
    const float scale = 0.03125f;  // 1024^-0.5
    const size_t MB = 1048576;

    if (ws_size >= 198 * MB) {
        // merged path: peak 198 MB
        u16* q   = (u16*)(ws + 0);            // 16384x1024 bf16 (q,kk contiguous)
        u16* kk  = (u16*)(ws + 32 * MB);
        u16* vT  = (u16*)(ws + 64 * MB);      // 8 x 1024 x 2048 bf16
        u16* ln3 = (u16*)(ws + 96 * MB);      // 3 x 16384x1024 bf16 (dead after proj)
        u16* wqb = (u16*)(ws + 192 * MB);     // 3 x 1024x1024 bf16
        u16* S   = (u16*)(ws + 96 * MB);      // 8x2048x2048 bf16 (aliases ln3)

        cast3_kernel<<<3072, 256, 0, stream>>>(Wq, Wk, Wv, wqb);
        ln3_kernel<<<49152, 256, 0, stream>>>(target, src_k, src_v,
                                              g_t, g_k, g_v, b_t, b_k, b_v, ln3);
        // Q/K/V projections: 256^2 8-phase kernel, one dispatch (z = projection)
        gemm8<4><<<dim3(64, 4, 3), 512, 0, stream>>>(ln3, wqb, bq, bk, bv,
            q, vT, 16384, 1024, 1024, 1.0f, 16777216L, 1048576L, 0);
        // P[b] = exp((q[b] @ k[b]^T) * scale): 256^2 8-phase
        gemm8<2><<<512, 512, 0, stream>>>(q, kk, nullptr, nullptr, nullptr, S, nullptr,
            2048, 2048, 1024, scale, 2048L * 1024, 2048L * 1024, 2048L * 2048);
        // out[b] = (P[b] @ vT[b]^T) / rowsum(P[b])  (old kernel; port later)
        gemm_bt<3><<<1024, 256, 0, stream>>>(S, vT, nullptr, nullptr, nullptr, d_out, nullptr,
            2048, 1024, 2048, 1.0f, 2048L * 2048, 1024L * 2048, 2048L * 1024);
    } else {
        // fallback (r6) path: peak ~140.5 MB
        u16* q   = (u16*)(ws + 0);
        u16* kk  = (u16*)(ws + 32 * MB);
        u16* vT  = (u16*)(ws + 64 * MB);
        u16* ln  = (u16*)(ws + 96 * MB);
        u16* wqb = (u16*)(ws + 128 * MB);
        u16* wkb = wqb + 1048576;
        u16* wvb = wkb + 1048576;
        u16* S   = (u16*)(ws + 96 * MB);

        cast3_kernel<<<3072, 256, 0, stream>>>(Wq, Wk, Wv, wqb);
        ln_cast_kernel<<<16384, 256, 0, stream>>>(target, g_t, b_t, ln);
        gemm_bt<0><<<dim3(128, 8, 1), 256, 0, stream>>>(ln, wqb, bq, nullptr, nullptr,
            q, nullptr, 16384, 1024, 1024, 1.0f, 0, 0, 0);
        ln_cast_kernel<<<16384, 256, 0, stream>>>(src_k, g_k, b_k, ln);
        gemm_bt<0><<<dim3(128, 8, 1), 256, 0, stream>>>(ln, wkb, bk, nullptr, nullptr,
            kk, nullptr, 16384, 1024, 1024, 1.0f, 0, 0, 0);
        ln_cast_kernel<<<16384, 256, 0, stream>>>(src_v, g_v, b_v, ln);
        gemm_bt<1><<<dim3(128, 8, 1), 256, 0, stream>>>(ln, wvb, bv, nullptr, nullptr,
            vT, nullptr, 16384, 1024, 1024, 1.0f, 0, 0, 0);
        gemm_bt<2><<<2048, 256, 0, stream>>>(q, kk, nullptr, nullptr, nullptr, S, nullptr,
            2048, 2048, 1024, scale, 2048L * 1024, 2048L * 1024, 2048L * 2048);
        gemm_bt<3><<<1024, 256, 0, stream>>>(S, vT, nullptr, nullptr, nullptr, d_out, nullptr,
            2048, 1024, 2048, 1.0f, 2048L * 2048, 1024L * 2048, 2048L * 1024);
    }
}

// Round 6
// 486.649 us; speedup vs baseline: 2.3672x; 1.0194x over previous
//
#include <hip/hip_runtime.h>
#include <cstdint>

using u16 = unsigned short;
using u32 = unsigned int;
typedef __attribute__((ext_vector_type(8))) short short8;
typedef __attribute__((ext_vector_type(4))) float f32x4;

__device__ __forceinline__ float bf2f(u16 u) { return __uint_as_float(((u32)u) << 16); }
__device__ __forceinline__ u16 f2bf(float f) {
    u32 u = __float_as_uint(f);
    u32 r = u + 0x7fffu + ((u >> 16) & 1u);   // round-to-nearest-even
    return (u16)(r >> 16);
}

__device__ __forceinline__ void load_lds16(const void* g, void* l) {
    __builtin_amdgcn_global_load_lds((const __attribute__((address_space(1))) void*)g,
                                     (__attribute__((address_space(3))) void*)l, 16, 0, 0);
}

// ---------------- LayerNorm row body (1024 fp32 -> bf16) ----------------
__device__ __forceinline__ void ln_row(const float* __restrict__ x,
                                       const float* __restrict__ gw,
                                       const float* __restrict__ bw,
                                       u16* __restrict__ y, int row) {
    const int tid = threadIdx.x;
    const float4 v = ((const float4*)(x + (size_t)row * 1024))[tid];
    float s  = v.x + v.y + v.z + v.w;
    float ss = v.x * v.x + v.y * v.y + v.z * v.z + v.w * v.w;
#pragma unroll
    for (int off = 32; off; off >>= 1) {
        s  += __shfl_xor(s, off);
        ss += __shfl_xor(ss, off);
    }
    __shared__ float sm[8];
    const int lane = tid & 63, wid = tid >> 6;
    if (lane == 0) { sm[wid] = s; sm[wid + 4] = ss; }
    __syncthreads();
    s  = sm[0] + sm[1] + sm[2] + sm[3];
    ss = sm[4] + sm[5] + sm[6] + sm[7];
    const float mu   = s * (1.0f / 1024.0f);
    const float var  = ss * (1.0f / 1024.0f) - mu * mu;
    const float rstd = rsqrtf(var + 1e-5f);
    const float4 g4 = ((const float4*)gw)[tid];
    const float4 b4 = ((const float4*)bw)[tid];
    u16 o[4];
    o[0] = f2bf((v.x - mu) * rstd * g4.x + b4.x);
    o[1] = f2bf((v.y - mu) * rstd * g4.y + b4.y);
    o[2] = f2bf((v.z - mu) * rstd * g4.z + b4.z);
    o[3] = f2bf((v.w - mu) * rstd * g4.w + b4.w);
    *(uint2*)(y + (size_t)row * 1024 + tid * 4) = *(uint2*)o;
}

__global__ __launch_bounds__(256)
void ln_cast_kernel(const float* __restrict__ x, const float* __restrict__ gw,
                    const float* __restrict__ bw, u16* __restrict__ y) {
    ln_row(x, gw, bw, y, blockIdx.x);
}

// merged: all 3 layernorms in one dispatch (sel = bid>>14)
__global__ __launch_bounds__(256)
void ln3_kernel(const float* __restrict__ x0, const float* __restrict__ x1,
                const float* __restrict__ x2,
                const float* __restrict__ g0, const float* __restrict__ g1,
                const float* __restrict__ g2,
                const float* __restrict__ b0, const float* __restrict__ b1,
                const float* __restrict__ b2, u16* __restrict__ y) {
    const int bid = blockIdx.x;
    const int sel = bid >> 14;
    const int row = bid & 16383;
    const float* x  = (sel == 0) ? x0 : (sel == 1) ? x1 : x2;
    const float* gw = (sel == 0) ? g0 : (sel == 1) ? g1 : g2;
    const float* bw = (sel == 0) ? b0 : (sel == 1) ? b1 : b2;
    ln_row(x, gw, bw, y + ((size_t)sel << 24), row);
}

// ---------------- fp32 -> bf16 cast of the 3 weight matrices ----------------
__global__ __launch_bounds__(256)
void cast3_kernel(const float* __restrict__ wa, const float* __restrict__ wb,
                  const float* __restrict__ wc, u16* __restrict__ oa) {
    const int bid = blockIdx.x;
    const int sel = bid >> 10;
    const float* s = (sel == 0) ? wa : (sel == 1) ? wb : wc;
    u16* d = oa + (size_t)sel * 1048576;
    const int i = (bid & 1023) * 256 + threadIdx.x;
    const float4 v = ((const float4*)s)[i];
    u16 o[4] = { f2bf(v.x), f2bf(v.y), f2bf(v.z), f2bf(v.w) };
    *(uint2*)(d + (size_t)i * 4) = *(uint2*)o;
}

// ---------------- zero the softmax-denominator buffer (64 KB) -------------
__global__ __launch_bounds__(256)
void zerof_kernel(float* __restrict__ p) {
    p[blockIdx.x * 256 + threadIdx.x] = 0.0f;
}

// ---------------- old 128x128 GEMM (fallback path only) -------------------
template<int MODE>
__global__ __launch_bounds__(256, (MODE == 3 ? 3 : 4))
void gemm_bt(const u16* __restrict__ A, const u16* __restrict__ B,
             const float* __restrict__ bias0, const float* __restrict__ bias1,
             const float* __restrict__ bias2,
             void* __restrict__ Cout, void* __restrict__ Cout2,
             const int M, const int N, const int K, const float scale,
             const long sA, const long sB, const long sC)
{
    int bz, m0, n0;
    if (MODE == 2 || MODE == 3) {
        const int id = blockIdx.x;
        bz = id & 7;                      // one batch per XCD
        m0 = ((id >> 3) & 15) * 128;
        n0 = (id >> 7) * 128;
    } else {
        bz = (MODE == 4) ? blockIdx.z : 0;
        m0 = blockIdx.x * 128;
        n0 = blockIdx.y * 128;
    }
    A += (long)bz * sA;
    B += (long)bz * sB;
    const float* bias = (MODE == 4) ? (bz == 0 ? bias0 : bz == 1 ? bias1 : bias2)
                                    : bias0;
    __shared__ __align__(16) u16 As[128 * 64];
    __shared__ __align__(16) u16 Bs[128 * 64];
    const int tid  = threadIdx.x;
    const int lane = tid & 63, wid = tid >> 6;
    const int wm = (wid & 1) * 64, wn = (wid >> 1) * 64;

    const int scol = (tid & 7) ^ ((tid >> 3) & 7);
    const u16* ap = A + (long)(m0 + (tid >> 3)) * K + scol * 8;
    const u16* bp = B + (long)(n0 + (tid >> 3)) * K + scol * 8;
    u16* asd = As + wid * 512;
    u16* bsd = Bs + wid * 512;
    const long rs32 = 32L * K;

    f32x4 acc[4][4] = {};
    f32x4 acc_l[4] = {};
    const short8 ones8 = {16256, 16256, 16256, 16256, 16256, 16256, 16256, 16256};
    const int fr = lane & 15, fq = lane >> 4;
    const int sw = (fq ^ (fr & 7)) * 8;
    const int offA0 = (wm + fr) * 64 + sw;
    const int offA1 = offA0 ^ 32;
    const int offB0 = (wn + fr) * 64 + sw;
    const int offB1 = offB0 ^ 32;

    for (int k0 = 0; k0 < K; k0 += 64) {
#pragma unroll
        for (int rd = 0; rd < 4; rd++) {
            load_lds16(ap + k0 + rd * rs32, asd + rd * 2048);
            load_lds16(bp + k0 + rd * rs32, bsd + rd * 2048);
        }
        __syncthreads();
#pragma unroll
        for (int s = 0; s < 2; s++) {
            const int oa = s ? offA1 : offA0;
            const int ob = s ? offB1 : offB0;
            short8 b0 = *(const short8*)&Bs[ob];
            short8 b1 = *(const short8*)&Bs[ob + 1024];
            short8 b2 = *(const short8*)&Bs[ob + 2048];
            short8 b3 = *(const short8*)&Bs[ob + 3072];
#pragma unroll
            for (int i = 0; i < 4; i++) {
                const short8 a = *(const short8*)&As[oa + i * 1024];
                acc[i][0] = __builtin_amdgcn_mfma_f32_16x16x32_bf16(a, b0, acc[i][0], 0, 0, 0);
                acc[i][1] = __builtin_amdgcn_mfma_f32_16x16x32_bf16(a, b1, acc[i][1], 0, 0, 0);
                acc[i][2] = __builtin_amdgcn_mfma_f32_16x16x32_bf16(a, b2, acc[i][2], 0, 0, 0);
                acc[i][3] = __builtin_amdgcn_mfma_f32_16x16x32_bf16(a, b3, acc[i][3], 0, 0, 0);
                if (MODE == 3)
                    acc_l[i] = __builtin_amdgcn_mfma_f32_16x16x32_bf16(a, ones8, acc_l[i], 0, 0, 0);
            }
        }
        __syncthreads();
    }

    const int cn = lane & 15;
    const int cm = (lane >> 4) * 4;
    float invl[4][4];
    if (MODE == 3) {
#pragma unroll
        for (int i = 0; i < 4; i++)
#pragma unroll
            for (int r = 0; r < 4; r++) invl[i][r] = 1.0f / acc_l[i][r];
    }
#pragma unroll
    for (int i = 0; i < 4; i++) {
        const int gmb = m0 + wm + i * 16 + cm;
#pragma unroll
        for (int j = 0; j < 4; j++) {
            const int gn = n0 + wn + j * 16 + cn;
            const float bv = (MODE <= 1 || MODE == 4) ? bias[gn] : 0.0f;
            if (MODE == 1 || (MODE == 4 && bz == 2)) {
                u16* dst = (MODE == 4) ? (u16*)Cout2 : (u16*)Cout;
                const int batch = gmb >> 11;
                const int jj = gmb & 2047;
                u16 o[4];
#pragma unroll
                for (int r = 0; r < 4; r++) o[r] = f2bf(acc[i][j][r] + bv);
                *(uint2*)(dst + ((long)batch * N + gn) * 2048 + jj) = *(uint2*)o;
            } else if (MODE == 0 || MODE == 4) {
                u16* dst = (u16*)Cout + ((MODE == 4) ? (long)bz * 16777216 : 0);
#pragma unroll
                for (int r = 0; r < 4; r++)
                    dst[(long)(gmb + r) * N + gn] = f2bf(acc[i][j][r] + bv);
            } else {
#pragma unroll
                for (int r = 0; r < 4; r++) {
                    const long gm = gmb + r;
                    float v = acc[i][j][r];
                    if (MODE == 2) v = __expf(v * scale);
                    if (MODE == 3)
                        ((float*)Cout)[(long)bz * sC + gm * N + gn] = v * invl[i][r];
                    else
                        ((u16*)Cout)[(long)bz * sC + gm * N + gn] = f2bf(v);
                }
            }
        }
    }
}

// ================= 256x256 8-phase quadrant GEMM (r12) ====================
// K-loop = r11 (verified). New in r12:
//  MODE 2: dots epilogue also computes softmax denominators: per-row fp32 sum
//          of the bf16-rounded exp values (same semantics as the old
//          ones-MFMA), reduced across the 16-lane fr-group via shfl_xor,
//          one device-scope atomicAdd per row per wave into L[8][2048]
//          (passed via Cout2).
//  MODE 5: PV = plain GEMM (A=S, B=vT, K=2048), epilogue scales by
//          1/L[row] (L via bias0) and stores fp32. Replaces gemm_bt<3>:
//          no ones-MFMA (-25% MFMA work), no acc_l registers, 256 blocks
//          = exactly 1 residency round.
__device__ __forceinline__ void ph_mid() {      // after reads+stage issued
    __builtin_amdgcn_sched_barrier(0);
    __builtin_amdgcn_s_barrier();
    asm volatile("s_waitcnt lgkmcnt(0)" ::: "memory");
    __builtin_amdgcn_sched_barrier(0);
}
__device__ __forceinline__ void ph_end() {      // after MFMA cluster
    __builtin_amdgcn_sched_barrier(0);
    __builtin_amdgcn_s_barrier();
    __builtin_amdgcn_sched_barrier(0);
}

// A-half quadrant mh: 4 m-tiles x 2 k-slices (8 x ds_read_b128)
#define RDAH(reg, mh) do { \
    aF[0] = *(const short8*)&(reg)[ offA + (mh)*8192 + 0*1024];        \
    aF[1] = *(const short8*)&(reg)[(offA + (mh)*8192 + 0*1024) ^ 32];  \
    aF[2] = *(const short8*)&(reg)[ offA + (mh)*8192 + 1*1024];        \
    aF[3] = *(const short8*)&(reg)[(offA + (mh)*8192 + 1*1024) ^ 32];  \
    aF[4] = *(const short8*)&(reg)[ offA + (mh)*8192 + 2*1024];        \
    aF[5] = *(const short8*)&(reg)[(offA + (mh)*8192 + 2*1024) ^ 32];  \
    aF[6] = *(const short8*)&(reg)[ offA + (mh)*8192 + 3*1024];        \
    aF[7] = *(const short8*)&(reg)[(offA + (mh)*8192 + 3*1024) ^ 32];  } while (0)

// B-half quadrant nh: 2 n-tiles x 2 k-slices (4 x ds_read_b128)
#define RDBH(dst, reg, nh) do { \
    dst[0] = *(const short8*)&(reg)[ offB + (nh)*8192 + 0*1024];        \
    dst[1] = *(const short8*)&(reg)[(offB + (nh)*8192 + 0*1024) ^ 32];  \
    dst[2] = *(const short8*)&(reg)[ offB + (nh)*8192 + 1*1024];        \
    dst[3] = *(const short8*)&(reg)[(offB + (nh)*8192 + 1*1024) ^ 32];  } while (0)

// one C-quadrant x K=64: 16 MFMA, k-slice OUTER (dep distance 8)
#define MMQ(mh, nh, bF) do { \
    __builtin_amdgcn_s_setprio(1); \
    _Pragma("unroll") \
    for (int s_ = 0; s_ < 2; s_++) { \
        _Pragma("unroll") \
        for (int i_ = 0; i_ < 4; i_++) { \
            _Pragma("unroll") \
            for (int j_ = 0; j_ < 2; j_++) \
                acc[(mh)*4+i_][(nh)*2+j_] = __builtin_amdgcn_mfma_f32_16x16x32_bf16( \
                    aF[2*i_+s_], bF[2*j_+s_], acc[(mh)*4+i_][(nh)*2+j_], 0, 0, 0); \
        } \
    } \
    __builtin_amdgcn_s_setprio(0); } while (0)

#define STA(reg, hm, kt) do { \
    const u16* s_ = apg + (hm) * rH + (long)(kt) * 64; \
    u16* d_ = (reg) + (hm) * 8192 + w * 1024; \
    load_lds16(s_, d_); \
    load_lds16(s_ + rK8, d_ + 512); } while (0)

#define STB(reg, hm, kt) do { \
    const u16* s_ = bpg + (hm) * rH + (long)(kt) * 64; \
    u16* d_ = (reg) + (hm) * 8192 + w * 1024; \
    load_lds16(s_, d_); \
    load_lds16(s_ + rK8, d_ + 512); } while (0)

// MODE 2: bf16 out = exp(acc*scale) + rowsum atomics into Cout2
// MODE 4: merged QKV, grid(M/256, N/256, 3); z<2 row-major +bias, z=2 vT
// MODE 5: fp32 out = acc / L[row]  (L via bias0)
template<int MODE>
__global__ __launch_bounds__(512, 1)
void gemm8(const u16* __restrict__ A, const u16* __restrict__ B,
           const float* __restrict__ bias0, const float* __restrict__ bias1,
           const float* __restrict__ bias2,
           void* __restrict__ Cout, void* __restrict__ Cout2,
           const int M, const int N, const int K, const float scale,
           const long sA, const long sB, const long sC)
{
    int bz, m0, n0;
    if (MODE == 2 || MODE == 5) {
        const int id = blockIdx.x;
        bz = id & 7;                      // one batch per XCD
        m0 = ((id >> 3) & 7) * 256;
        n0 = (id >> 6) * 256;
    } else {
        bz = blockIdx.z;
        m0 = blockIdx.x * 256;
        n0 = blockIdx.y * 256;
    }
    A += (long)bz * sA;
    B += (long)bz * sB;
    const float* bias = (MODE == 4) ? (bz == 0 ? bias0 : bz == 1 ? bias1 : bias2)
                                    : bias0;

    __shared__ __align__(16) u16 lds[65536];   // 128 KiB
    u16* const Ar0 = lds;
    u16* const Ar1 = lds + 16384;
    u16* const Br0 = lds + 32768;
    u16* const Br1 = lds + 49152;

    const int tid = threadIdx.x;
    const int w = tid >> 6, l = tid & 63;
    // staging: wave w covers rows w*16 + (l>>3) (+8 for 2nd load) of a
    // 128-row half; global col-group pre-swizzled so the linear LDS fill
    // realizes LDS[r*64 + ((cg ^ (r&7))*8)] = global cols cg*8.. of row r.
    const int cgrp = (l & 7) ^ ((l >> 3) & 7);
    const long rK8 = 8L * K;
    const long rH  = 128L * K;
    const u16* apg = A + (long)(m0 + w * 16 + (l >> 3)) * K + cgrp * 8;
    const u16* bpg = B + (long)(n0 + w * 16 + (l >> 3)) * K + cgrp * 8;

    const int w1 = w & 1;                 // M sub-band within a 128-row half
    const int wn2 = (w >> 1) * 32;        // N sub-band within a 128-col half
    const int fr = l & 15, fq = l >> 4;
    const int sw8 = (fq ^ (fr & 7)) * 8;
    const int offA = (w1 * 64 + fr) * 64 + sw8;   // + mh*8192 + i*1024
    const int offB = (wn2 + fr) * 64 + sw8;       // + nh*8192 + j*1024

    f32x4 acc[8][4] = {};
    short8 aF[8];
    short8 bF0[4], bF1[4];

    // prologue: tile0 -> buf0, tile1 -> buf1 (B-halves then A-halves each)
    STB(Br0, 0, 0); STB(Br0, 1, 0); STA(Ar0, 0, 0); STA(Ar0, 1, 0);
    STB(Br1, 0, 1); STB(Br1, 1, 1); STA(Ar1, 0, 1); STA(Ar1, 1, 1);
    __builtin_amdgcn_sched_barrier(0);
    asm volatile("s_waitcnt vmcnt(8)" ::: "memory");   // tile0 landed
    __builtin_amdgcn_s_barrier();
    asm volatile("" ::: "memory");
    __builtin_amdgcn_sched_barrier(0);

    const int NI = K >> 7;                // 2 K-tiles per iteration
    for (int it = 0; it < NI; ++it) {
        const bool nl = (it < NI - 1);
        const int t2 = 2 * it + 2, t3 = 2 * it + 3;
        // ---- tile 2it from buf0 ----
        // P1: rd A-q0 (8) + B-q0 (4); MFMA Q00   (touches halves Ah0, Bh0)
        RDAH(Ar0, 0); RDBH(bF0, Br0, 0);
        ph_mid();
        MMQ(0, 0, bF0);
        ph_end();
        // P2: rd B-q1 (4, half Bh1); stage Bh0(t2)+Ah0(t2); MFMA Q01
        RDBH(bF1, Br0, 1);
        if (nl) { STB(Br0, 0, t2); STA(Ar0, 0, t2); }
        ph_mid();
        MMQ(0, 1, bF1);
        ph_end();
        // P3: rd A-q1 (8, half Ah1); stage Bh1(t2); MFMA Q10
        RDAH(Ar0, 1);
        if (nl) STB(Br0, 1, t2);
        ph_mid();
        MMQ(1, 0, bF0);
        ph_end();
        // P4: stage Ah1(t2); MFMA Q11; gate vmcnt -> buf1 (odd tile) landed
        if (nl) STA(Ar0, 1, t2);
        ph_mid();
        MMQ(1, 1, bF1);
        __builtin_amdgcn_sched_barrier(0);
        if (nl) asm volatile("s_waitcnt vmcnt(8)" ::: "memory");
        else    asm volatile("s_waitcnt vmcnt(0)" ::: "memory");
        __builtin_amdgcn_s_barrier();
        asm volatile("" ::: "memory");
        __builtin_amdgcn_sched_barrier(0);
        // ---- tile 2it+1 from buf1 ----
        // P5: rd A-q0 + B-q0; MFMA Q00
        RDAH(Ar1, 0); RDBH(bF0, Br1, 0);
        ph_mid();
        MMQ(0, 0, bF0);
        ph_end();
        // P6: rd B-q1; stage Bh0(t3)+Ah0(t3); MFMA Q01
        RDBH(bF1, Br1, 1);
        if (nl) { STB(Br1, 0, t3); STA(Ar1, 0, t3); }
        ph_mid();
        MMQ(0, 1, bF1);
        ph_end();
        // P7: rd A-q1; stage Bh1(t3); MFMA Q10
        RDAH(Ar1, 1);
        if (nl) STB(Br1, 1, t3);
        ph_mid();
        MMQ(1, 0, bF0);
        ph_end();
        // P8: stage Ah1(t3); MFMA Q11; gate vmcnt -> buf0 (t2) landed
        if (nl) STA(Ar1, 1, t3);
        ph_mid();
        MMQ(1, 1, bF1);
        __builtin_amdgcn_sched_barrier(0);
        if (nl) asm volatile("s_waitcnt vmcnt(8)" ::: "memory");
        else    asm volatile("s_waitcnt vmcnt(0)" ::: "memory");
        __builtin_amdgcn_s_barrier();
        asm volatile("" ::: "memory");
        __builtin_amdgcn_sched_barrier(0);
    }

    // epilogue: C/D layout col=lane&15, row=(lane>>4)*4+r
    // acc[i][j]: global row = m0 + (i>>2)*128 + w1*64 + (i&3)*16 + cm
    //            global col = n0 + (j>>1)*128 + wn2 + (j&1)*16 + cn
    const int cn = l & 15, cm = (l >> 4) * 4;
#pragma unroll
    for (int i = 0; i < 8; i++) {
        const int gmb = m0 + (i >> 2) * 128 + w1 * 64 + (i & 3) * 16 + cm;
        float inv[4];
        if (MODE == 5) {
            const float4 l4 = *(const float4*)(bias + (long)bz * 2048 + gmb);
            inv[0] = 1.0f / l4.x; inv[1] = 1.0f / l4.y;
            inv[2] = 1.0f / l4.z; inv[3] = 1.0f / l4.w;
        }
        float rs[4] = {0.0f, 0.0f, 0.0f, 0.0f};   // MODE 2 row partial sums
#pragma unroll
        for (int j = 0; j < 4; j++) {
            const int gn = n0 + (j >> 1) * 128 + wn2 + (j & 1) * 16 + cn;
            if (MODE == 4) {
                const float bv = bias[gn];
                if (bz == 2) {
                    const int batch = gmb >> 11, jj = gmb & 2047;
                    u16 o[4];
#pragma unroll
                    for (int r = 0; r < 4; r++) o[r] = f2bf(acc[i][j][r] + bv);
                    *(uint2*)((u16*)Cout2 + ((long)batch * N + gn) * 2048 + jj) = *(uint2*)o;
                } else {
                    u16* dst = (u16*)Cout + (long)bz * ((long)M * N);
#pragma unroll
                    for (int r = 0; r < 4; r++)
                        dst[(long)(gmb + r) * N + gn] = f2bf(acc[i][j][r] + bv);
                }
            } else if (MODE == 5) {
#pragma unroll
                for (int r = 0; r < 4; r++)
                    ((float*)Cout)[(long)bz * sC + (long)(gmb + r) * N + gn] =
                        acc[i][j][r] * inv[r];
            } else {  // MODE 2
#pragma unroll
                for (int r = 0; r < 4; r++) {
                    const float e = __expf(acc[i][j][r] * scale);
                    const u16 h = f2bf(e);
                    ((u16*)Cout)[(long)bz * sC + (long)(gmb + r) * N + gn] = h;
                    rs[r] += bf2f(h);
                }
            }
        }
        if (MODE == 2) {
            // reduce each row sum across the 16-lane fr-group, one atomic/row
#pragma unroll
            for (int r = 0; r < 4; r++) {
                float s = rs[r];
                s += __shfl_xor(s, 1);
                s += __shfl_xor(s, 2);
                s += __shfl_xor(s, 4);
                s += __shfl_xor(s, 8);
                if (fr == 0)
                    atomicAdd((float*)Cout2 + (long)bz * 2048 + gmb + r, s);
            }
        }
    }
}

extern "C" void kernel_launch(void* const* d_in, const int* in_sizes, int n_in,
                              void* d_out, int out_size, void* d_ws, size_t ws_size,
                              hipStream_t stream) {
    const float* target = (const float*)d_in[0];
    const float* src_k  = (const float*)d_in[1];
    const float* src_v  = (const float*)d_in[2];
    const float* Wq = (const float*)d_in[3];
    const float* bq = (const float*)d_in[4];
    const float* Wk = (const float*)d_in[5];
    const float* bk = (const float*)d_in[6];
    const float* Wv = (const float*)d_in[7];
    const float* bv = (const float*)d_in[8];
    const float* g_t = (const float*)d_in[9];
    const float* b_t = (const float*)d_in[10];
    const float* g_k = (const float*)d_in[11];
    const float* b_k = (const float*)d_in[12];
    const float* g_v = (const float*)d_in[13];
    const float* b_v = (const float*)d_in[14];

    char* ws = (char*)d_ws;
    const float scale = 0.03125f;  // 1024^-0.5
    const size_t MB = 1048576;

    if (ws_size >= 198 * MB) {
        // merged path: peak 198 MB
        u16* q   = (u16*)(ws + 0);            // 16384x1024 bf16 (q,kk contiguous)
        u16* kk  = (u16*)(ws + 32 * MB);
        u16* vT  = (u16*)(ws + 64 * MB);      // 8 x 1024 x 2048 bf16
        u16* ln3 = (u16*)(ws + 96 * MB);      // 3 x 16384x1024 bf16 (dead after proj)
        u16* wqb = (u16*)(ws + 192 * MB);     // 3 x 1024x1024 bf16
        u16* S   = (u16*)(ws + 96 * MB);      // 8x2048x2048 bf16 = 96..160 MB
        float* L = (float*)(ws + 160 * MB);   // 8x2048 fp32 denominators (dead ln3 tail)

        cast3_kernel<<<3072, 256, 0, stream>>>(Wq, Wk, Wv, wqb);
        ln3_kernel<<<49152, 256, 0, stream>>>(target, src_k, src_v,
                                              g_t, g_k, g_v, b_t, b_k, b_v, ln3);
        // Q/K/V projections: 256^2 8-phase kernel, one dispatch (z = projection)
        gemm8<4><<<dim3(64, 4, 3), 512, 0, stream>>>(ln3, wqb, bq, bk, bv,
            q, vT, 16384, 1024, 1024, 1.0f, 16777216L, 1048576L, 0);
        // zero denominators (must be after QKV: L aliases dead ln3 space)
        zerof_kernel<<<64, 256, 0, stream>>>(L);
        // P[b] = exp((q[b] @ k[b]^T) * scale), rowsums -> L
        gemm8<2><<<512, 512, 0, stream>>>(q, kk, nullptr, nullptr, nullptr, S, L,
            2048, 2048, 1024, scale, 2048L * 1024, 2048L * 1024, 2048L * 2048);
        // out[b] = (P[b] @ vT[b]^T) / L[row]
        gemm8<5><<<256, 512, 0, stream>>>(S, vT, L, nullptr, nullptr, d_out, nullptr,
            2048, 1024, 2048, 1.0f, 2048L * 2048, 1024L * 2048, 2048L * 1024);
    } else {
        // fallback (r6) path: peak ~140.5 MB
        u16* q   = (u16*)(ws + 0);
        u16* kk  = (u16*)(ws + 32 * MB);
        u16* vT  = (u16*)(ws + 64 * MB);
        u16* ln  = (u16*)(ws + 96 * MB);
        u16* wqb = (u16*)(ws + 128 * MB);
        u16* wkb = wqb + 1048576;
        u16* wvb = wkb + 1048576;
        u16* S   = (u16*)(ws + 96 * MB);

        cast3_kernel<<<3072, 256, 0, stream>>>(Wq, Wk, Wv, wqb);
        ln_cast_kernel<<<16384, 256, 0, stream>>>(target, g_t, b_t, ln);
        gemm_bt<0><<<dim3(128, 8, 1), 256, 0, stream>>>(ln, wqb, bq, nullptr, nullptr,
            q, nullptr, 16384, 1024, 1024, 1.0f, 0, 0, 0);
        ln_cast_kernel<<<16384, 256, 0, stream>>>(src_k, g_k, b_k, ln);
        gemm_bt<0><<<dim3(128, 8, 1), 256, 0, stream>>>(ln, wkb, bk, nullptr, nullptr,
            kk, nullptr, 16384, 1024, 1024, 1.0f, 0, 0, 0);
        ln_cast_kernel<<<16384, 256, 0, stream>>>(src_v, g_v, b_v, ln);
        gemm_bt<1><<<dim3(128, 8, 1), 256, 0, stream>>>(ln, wvb, bv, nullptr, nullptr,
            vT, nullptr, 16384, 1024, 1024, 1.0f, 0, 0, 0);
        gemm_bt<2><<<2048, 256, 0, stream>>>(q, kk, nullptr, nullptr, nullptr, S, nullptr,
            2048, 2048, 1024, scale, 2048L * 1024, 2048L * 1024, 2048L * 2048);
        gemm_bt<3><<<1024, 256, 0, stream>>>(S, vT, nullptr, nullptr, nullptr, d_out, nullptr,
            2048, 1024, 2048, 1.0f, 2048L * 2048, 1024L * 2048, 2048L * 1024);
    }
}